// Round 10
// baseline (176.480 us; speedup 1.0000x reference)
//
#include <hip/hip_runtime.h>

// SLAYER constants
#define ALPHA  0.90483741803595952f   /* exp(-1/10) */
#define ALPHA8 0.44932896411722156f   /* exp(-0.8)  */
#define A64C   5.82e-23f              /* ALPHA8^64 = exp(-51.2), negligible tail */
#define THETA  10.0f
#define BF1    ((unsigned short)0x3F80) /* 1.0f as bf16 */
#define ISCALE 0.015625f               /* 1/64, exact */

typedef short   bf16x8 __attribute__((ext_vector_type(8)));
typedef float   f32x4  __attribute__((ext_vector_type(4)));
typedef float   f32x4v __attribute__((ext_vector_type(4)));
typedef unsigned short ushort4v __attribute__((ext_vector_type(4)));
typedef unsigned short ushort8v __attribute__((ext_vector_type(8)));
typedef unsigned char  uchar4v  __attribute__((ext_vector_type(4)));
typedef unsigned char  uchar8v  __attribute__((ext_vector_type(8)));
typedef long long i64;

// async global->LDS DMA, 16 B per lane. LDS dest = wave-uniform base + lane*16
#define DMA16(gsrc, ldst)                                                     \
    __builtin_amdgcn_global_load_lds(                                         \
        (const __attribute__((address_space(1))) unsigned int*)(gsrc),        \
        (__attribute__((address_space(3))) unsigned int*)(ldst), 16, 0, 0)

// HW transpose-read: 4x16 bf16 subtile, lane l elem j <- lds[(l&15)*2 + j*32
// + (l>>4)*128 + vaddr].  AS3 pointer (32-bit) as vaddr.
__device__ __forceinline__ i64 tr16(const unsigned char* p) {
    i64 r;
    asm volatile("ds_read_b64_tr_b16 %0, %1"
                 : "=v"(r)
                 : "v"((const __attribute__((address_space(3))) unsigned char*)p));
    return r;
}

// RNE float -> bf16 bits
__device__ __forceinline__ unsigned short f2bf(float f) {
    unsigned int x = __float_as_uint(f);
    unsigned int r = (x + 0x7FFFu + ((x >> 16) & 1u)) >> 16;
    return (unsigned short)r;
}
__device__ __forceinline__ float bf2f(unsigned short h) {
    return __uint_as_float(((unsigned int)h) << 16);
}
// 2-way bf16 split: w ~= h0+h1 (residual ~2^-17 rel)
__device__ __forceinline__ void split2(float w, unsigned short& h0,
                                       unsigned short& h1) {
    h0 = f2bf(w);          float r0 = w - bf2f(h0);
    h1 = f2bf(r0);
}
// HW fp8 converts
__device__ __forceinline__ unsigned char f2fp8(float f) {
    int pk = __builtin_amdgcn_cvt_pk_fp8_f32(f, 0.f, 0, false);
    return (unsigned char)(pk & 0xFF);
}
__device__ __forceinline__ float fp82f(unsigned char b) {
    return __builtin_amdgcn_cvt_f32_fp8((int)b, 0);
}

// ---------------------------------------------------------------------------
// prep_scan_pack: fused input prep + weight packing.
// Pbf is now [32][160][2048] (c padded to 160 with ZERO rows) so mega_gemm1
// can stage B directly from it (transposeP kernel deleted).
// Blocks: [0,1088) weight packs, [1088,6080) input rows, [6080,6208) zero-pad.
// ---------------------------------------------------------------------------
__global__ __launch_bounds__(256) void prep_scan_pack(
    const float* __restrict__ In, unsigned char* __restrict__ Infp8,
    unsigned short* __restrict__ Pbf,
    const float* __restrict__ W1,  const float* __restrict__ W2,
    const float* __restrict__ Wl1, const float* __restrict__ Wl2,
    unsigned short* __restrict__ W1p,  unsigned char* __restrict__ W2p8,
    unsigned char* __restrict__ Wl1p8, unsigned short* __restrict__ Wl2p)
{
    const int blk = blockIdx.x;
    const int tid = threadIdx.x;
    if (blk >= 6080) {                          // Pbf zero-pad rows c=156..159
        int idx = blk - 6080;
        int b = idx >> 2, c = 156 + (idx & 3);
        ushort8v z = {0,0,0,0,0,0,0,0};
        *(ushort8v*)(Pbf + (long long)(b * 160 + c) * 2048 + tid * 8) = z;
        return;
    }
    if (blk < 1088) {
        if (blk < 512) {                            // Wl1 -> fp8 split-2, x64
            int m = blk;
            for (int k = tid; k < 2048; k += 256) {
                float w = Wl1[(long long)m * 2048 + k] * 64.0f;
                unsigned char h0 = f2fp8(w);
                unsigned char h1 = f2fp8(w - fp82f(h0));
                Wl1p8[(long long)m * 2048 + k] = h0;
                Wl1p8[1048576 + (long long)m * 2048 + k] = h1;
            }
        } else if (blk < 1024) {                    // W1 -> bf16 split-2
            int m = blk - 512;
            for (int k = tid; k < 160; k += 256) {
                float v = (k < 156) ? W1[(long long)m * 156 + k] : 0.f;
                unsigned short h0, h1;
                split2(v, h0, h1);
                W1p[(long long)m * 160 + k] = h0;
                W1p[81920 + (long long)m * 160 + k] = h1;
            }
        } else if (blk < 1056) {                    // W2 -> fp8 split-2
            int m = blk - 1024;
            for (int k = tid; k < 512; k += 256) {
                float w = (m < 20) ? W2[(long long)m * 512 + k] : 0.f;
                unsigned char h0 = f2fp8(w);
                unsigned char h1 = f2fp8(w - fp82f(h0));
                W2p8[(long long)m * 512 + k] = h0;
                W2p8[16384 + (long long)m * 512 + k] = h1;
            }
        } else {                                    // Wl2 -> bf16 split-2
            int m = blk - 1056;
            for (int k = tid; k < 512; k += 256) {
                float v = (m < 20) ? Wl2[(long long)m * 512 + k] : 0.f;
                unsigned short h0, h1;
                split2(v, h0, h1);
                Wl2p[(long long)m * 512 + k] = h0;
                Wl2p[16384 + (long long)m * 512 + k] = h1;
            }
        }
        return;
    }

    const int row = blk - 1088;
    const int bN  = row / 156;
    const int prow = bN * 160 + (row - bN * 156);
    const float* x = In + (long long)row * 2048 + tid * 8;
    const unsigned char ONE8 = f2fp8(1.0f);

    float v[8];
    *(f32x4v*)&v[0] = *(const f32x4v*)x;
    *(f32x4v*)&v[4] = *(const f32x4v*)(x + 4);

    uchar8v raw;
    #pragma unroll
    for (int k = 0; k < 8; ++k) raw[k] = (v[k] >= 0.5f) ? ONE8 : (unsigned char)0;
    *(uchar8v*)(Infp8 + (long long)row * 2048 + tid * 8) = raw;

    float y = 0.f;
    #pragma unroll
    for (int k = 0; k < 8; ++k) { y = ALPHA * y + v[k]; v[k] = y; }

    const int lane = tid & 63, wid = tid >> 6;
    float val = y, mm = ALPHA8;
    #pragma unroll
    for (int d = 1; d < 64; d <<= 1) {
        float p = __shfl_up(val, d);
        if (lane >= d) val += mm * p;
        mm *= mm;
    }
    __shared__ float wsum[4];
    if (lane == 63) wsum[wid] = val;
    __syncthreads();
    float pw = 0.f;
    #pragma unroll
    for (int w2 = 0; w2 < 3; ++w2)
        if (w2 < wid) pw = pw * A64C + wsum[w2];
    float prev = __shfl_up(val, 1);
    float a8l  = __expf(-0.8f * (float)lane);
    float carry = (lane == 0) ? pw : (prev + a8l * pw);

    ushort8v pv;
    float ak = ALPHA;
    #pragma unroll
    for (int k = 0; k < 8; ++k) {
        float yk = v[k] + ak * carry;
        ak *= ALPHA;
        pv[k] = f2bf(yk);
    }
    *(ushort8v*)(Pbf + (long long)prow * 2048 + tid * 8) = pv;
}

// ---------------------------------------------------------------------------
// MEGA1: blocks [0,1280)    = branch-2 GEMM1 (fp8, split-K x4) — first (LPT)
//        blocks [1280,3328) = branch-1 GEMM1 (bf16, 128x128 tile)
// branch-1 B now staged DIRECTLY from Pbf [b][160 c][2048 t] into a tr16-
// compatible subtiled LDS layout ([c/4][t/16][4][16], byte(c,t) =
// (c>>2)*1024+(t>>4)*128+(c&3)*32+(t&15)*2; DMA dest stays lane*16 linear),
// fragments read via ds_read_b64_tr_b16 — transposeP kernel DELETED.
// c >= 156 rows are zeros in Pbf (and W1p zero-pads k>=156).
// ---------------------------------------------------------------------------
__global__ __launch_bounds__(256) void mega_gemm1(
    const unsigned short* __restrict__ W1p,
    const unsigned short* __restrict__ Pbf,  // [32][160][2048] bf16
    unsigned short* __restrict__ S1bits,     // [32][128 nchunk][512 m]
    const unsigned char* __restrict__ Wl1p8, // [2][512][2048] fp8
    const unsigned char* __restrict__ Infp8, // [4992][2048] fp8
    unsigned short* __restrict__ Zp)         // [4][156][16384] c-major bf16
{
    __shared__ alignas(16) unsigned char SMEM[49152];
    const int bx  = blockIdx.x;
    const int tid = threadIdx.x;
    const int lane = tid & 63, w = tid >> 6;
    const int wy = w >> 1, wx = w & 1;
    const int l15 = lane & 15, kq = lane >> 4;
    const int key = (l15 >> 1) & 3;          // swizzle key (A-side)

    if (bx >= 1280) {
        // ========== branch-1 GEMM1 (bf16, 128x128, DMA staging) ==========
        unsigned char* Ab = SMEM;                  // [2buf][2pl][128m][32k] 2x16384
        unsigned char* Bb = SMEM + 32768;          // [2buf] tr16-subtiled   2x8192

        const int id1 = bx - 1280;
        const int z  = id1 >> 6;
        const int m0 = ((id1 >> 4) & 3) * 128;
        const int n0 = (id1 & 15) * 128;

        const unsigned short* gA[4]; int ldsA[4];
        #pragma unroll
        for (int s = 0; s < 4; ++s) {
            int id = tid + s * 256;
            int pl = id >> 9, m = (id >> 2) & 127, g = id & 3;
            int gs = g ^ ((m >> 1) & 3);
            gA[s] = W1p + (long long)pl * 81920 + (long long)(m0 + m) * 160 + gs * 8;
            ldsA[s] = id * 16;
        }
        // B source: lane id -> (c, t8) of the subtiled layout (dest = id*16)
        const unsigned short* gB[2];
        #pragma unroll
        for (int s = 0; s < 2; ++s) {
            int id = tid + s * 256;
            int c  = ((id >> 6) << 2) | ((id >> 1) & 3);
            int t8 = ((((id >> 3) & 7) << 1) | (id & 1)) << 3;
            gB[s] = Pbf + (long long)(z * 160 + c) * 2048 + n0 + t8;
        }

        auto dmaA = [&](int buf) {
            unsigned char* dst = Ab + buf * 16384;
            #pragma unroll
            for (int s = 0; s < 4; ++s) { DMA16(gA[s], dst + ldsA[s]); gA[s] += 32; }
        };
        auto dmaB = [&](int buf) {
            unsigned char* dst = Bb + buf * 8192;
            #pragma unroll
            for (int s = 0; s < 2; ++s) {
                DMA16(gB[s], dst + (tid + s * 256) * 16);
                gB[s] += 65536;                  // +32 c rows
            }
        };

        int aOff[2][4];
        #pragma unroll
        for (int pl = 0; pl < 2; ++pl)
            #pragma unroll
            for (int mt = 0; mt < 4; ++mt)
                aOff[pl][mt] = pl * 8192 + (wy * 64 + mt * 16 + l15) * 64 +
                               ((kq ^ key) * 16);
        // tr16 base: quarter skew kq*1920 (+ HW kq*128 = subtile stride 2048)
        const int bTr = wx * 512 + kq * 1920;

        f32x4 acc[4][4] = {};

        dmaA(0); dmaB(0);
        __syncthreads();

        #pragma unroll
        for (int it = 0; it < 5; ++it) {
            const int cur = it & 1;
            if (it < 4) { dmaA(cur ^ 1); dmaB(cur ^ 1); }

            const unsigned char* Ac = Ab + cur * 16384;
            const unsigned char* vB = Bb + cur * 8192 + bTr;
            bf16x8 bfr[4];
            #pragma unroll
            for (int nt = 0; nt < 4; ++nt) {
                union { i64 q[2]; bf16x8 v; } u;
                u.q[0] = tr16(vB + nt * 128);            // c = kq*8+0..3
                u.q[1] = tr16(vB + 1024 + nt * 128);     // c = kq*8+4..7
                bfr[nt] = u.v;
            }
            asm volatile("s_waitcnt lgkmcnt(0)" ::: "memory");
            __builtin_amdgcn_sched_barrier(0);

            #pragma unroll
            for (int pl = 0; pl < 2; ++pl) {
                #pragma unroll
                for (int mt = 0; mt < 4; ++mt) {
                    bf16x8 afr = *(const bf16x8*)(Ac + aOff[pl][mt]);
                    #pragma unroll
                    for (int nt = 0; nt < 4; ++nt)
                        acc[mt][nt] = __builtin_amdgcn_mfma_f32_16x16x32_bf16(
                            afr, bfr[nt], acc[mt][nt], 0, 0, 0);
                }
            }
            __syncthreads();
        }

        unsigned short* Db = S1bits + (long long)z * 512 * 128;
        #pragma unroll
        for (int mt = 0; mt < 4; ++mt) {
            #pragma unroll
            for (int i = 0; i < 4; ++i) {
                int m = m0 + wy * 64 + mt * 16 + kq * 4 + i;
                #pragma unroll
                for (int nt = 0; nt < 4; ++nt) {
                    unsigned long long mask = __ballot(acc[mt][nt][i] >= THETA);
                    if (l15 == 0) {
                        int nchunk = (n0 + wx * 64 + nt * 16) >> 4;
                        Db[(long long)nchunk * 512 + m] =
                            (unsigned short)((mask >> (kq * 16)) & 0xFFFFu);
                    }
                }
            }
        }
    } else {
        // ========== branch-2 GEMM1 (fp8, 64x128, DMA staging) ==========
        unsigned char* Ab = SMEM;                  // [2buf][2pl][64m][64k] 2x8192
        unsigned char* Bb = SMEM + 16384;          // [2buf][128n][64k]     2x8192

        const int id0 = bx;
        const int nIdx = id0 % 40;
        if (nIdx >= 39) return;
        const int rest = id0 / 40;
        const int n0  = nIdx * 128;
        const int m0  = (rest & 7) * 64;
        const int ksl = rest >> 3;
        const int ks0 = ksl * 512;

        const unsigned char* gA8[2]; int ldsA8[2];
        #pragma unroll
        for (int s = 0; s < 2; ++s) {
            int id = tid + s * 256;
            int pl = id >> 8, m = (id >> 2) & 63, g = id & 3;
            int gs = g ^ ((m >> 1) & 3);
            gA8[s] = Wl1p8 + (long long)pl * 1048576 +
                     (long long)(m0 + m) * 2048 + ks0 + gs * 16;
            ldsA8[s] = id * 16;
        }
        const unsigned char* gB8[2]; int ldsB8[2];
        #pragma unroll
        for (int s = 0; s < 2; ++s) {
            int id = tid + s * 256;
            int n = id >> 2, g = id & 3;
            int gs = g ^ ((n >> 1) & 3);
            gB8[s] = Infp8 + (long long)(n0 + n) * 2048 + ks0 + gs * 16;
            ldsB8[s] = id * 16;
        }

        auto dmaA8 = [&](int buf) {
            unsigned char* dst = Ab + buf * 8192;
            #pragma unroll
            for (int s = 0; s < 2; ++s) { DMA16(gA8[s], dst + ldsA8[s]); gA8[s] += 64; }
        };
        auto dmaB8 = [&](int buf) {
            unsigned char* dst = Bb + buf * 8192;
            #pragma unroll
            for (int s = 0; s < 2; ++s) { DMA16(gB8[s], dst + ldsB8[s]); gB8[s] += 64; }
        };

        int aO8[2][2][2], bO8[4][2];
        #pragma unroll
        for (int ks = 0; ks < 2; ++ks) {
            const int gl = ks * 2 + (kq >> 1);
            const int sub = ((gl ^ key) * 16) + (kq & 1) * 8;
            #pragma unroll
            for (int pl = 0; pl < 2; ++pl)
                #pragma unroll
                for (int mt = 0; mt < 2; ++mt)
                    aO8[pl][mt][ks] = pl * 4096 +
                        (wy * 32 + mt * 16 + l15) * 64 + sub;
            #pragma unroll
            for (int nt = 0; nt < 4; ++nt)
                bO8[nt][ks] = (wx * 64 + nt * 16 + l15) * 64 + sub;
        }

        f32x4 acc[2][4] = {};

        dmaA8(0); dmaB8(0);
        __syncthreads();

        #pragma unroll
        for (int it = 0; it < 8; ++it) {
            const int cur = it & 1;
            if (it < 7) { dmaA8(cur ^ 1); dmaB8(cur ^ 1); }

            const unsigned char* Ac = Ab + cur * 8192;
            const unsigned char* Bc = Bb + cur * 8192;
            #pragma unroll
            for (int ks = 0; ks < 2; ++ks) {
                i64 bfr[4];
                #pragma unroll
                for (int nt = 0; nt < 4; ++nt)
                    bfr[nt] = *(const i64*)(Bc + bO8[nt][ks]);
                #pragma unroll
                for (int pl = 0; pl < 2; ++pl) {
                    #pragma unroll
                    for (int mt = 0; mt < 2; ++mt) {
                        i64 afr = *(const i64*)(Ac + aO8[pl][mt][ks]);
                        #pragma unroll
                        for (int nt = 0; nt < 4; ++nt)
                            acc[mt][nt] = __builtin_amdgcn_mfma_f32_16x16x32_fp8_fp8(
                                afr, bfr[nt], acc[mt][nt], 0, 0, 0);
                    }
                }
            }
            __syncthreads();
        }

        unsigned short* Tu = (unsigned short*)SMEM;   // [64][130] overlay (odd banks)
        #pragma unroll
        for (int mt = 0; mt < 2; ++mt) {
            #pragma unroll
            for (int i = 0; i < 4; ++i) {
                int mL = wy * 32 + mt * 16 + kq * 4 + i;
                #pragma unroll
                for (int nt = 0; nt < 4; ++nt) {
                    int nL = wx * 64 + nt * 16 + l15;
                    Tu[mL * 130 + nL] = f2bf(acc[mt][nt][i] * ISCALE);
                }
            }
        }
        __syncthreads();

        unsigned short* Zs = Zp + (long long)ksl * 2555904;
        #pragma unroll
        for (int s2 = 0; s2 < 32; ++s2) {
            int id = tid + s2 * 256;
            int cL = id >> 6;
            int mL = id & 63;
            int n = n0 + cL;
            int bb = n / 156, cc = n - bb * 156;
            Zs[(long long)cc * 16384 + bb * 512 + m0 + mL] = Tu[mL * 130 + cL];
        }
    }
}

// ---------------------------------------------------------------------------
// MEGA2: blocks [0,512)    = branch-2 scan_sum4_perm (LDS-staged) — first
//        blocks [512,1024) = branch-1 GEMM2 (fp8 MFMA, full K=512)  (r9)
// ---------------------------------------------------------------------------
__global__ __launch_bounds__(256) void mega_stage2(
    const unsigned char* __restrict__ W2p8,
    const unsigned short* __restrict__ S1bits,   // [32][128 nchunk][512 m]
    float* __restrict__ C2p,                     // [32][20][2048] final
    const unsigned short* __restrict__ Zp,
    const int* __restrict__ perm,
    unsigned short* __restrict__ L1T)
{
    __shared__ alignas(16) unsigned char SMEM[27648];
    const int bx  = blockIdx.x;
    const int tid = threadIdx.x;

    if (bx >= 512) {
        auto As = (unsigned char (*)[2][32][72])SMEM;         // [buf][pl][32][72] : 2x4608
        auto Bs = (unsigned char (*)[128][72])(SMEM + 9216);  // [buf][128][72]    : 2x9216

        const int bxg = bx - 512;
        const int lane = tid & 63, w = tid >> 6;
        const int l15 = lane & 15, kq = lane >> 4;
        const int n0  = (bxg & 15) * 128;
        const int b   = bxg >> 4;

        const unsigned short* Bb = S1bits + (long long)b * 512 * 128;
        const unsigned char ONE8 = f2fp8(1.0f);

        int aPl[2], aM[2], aK8[2];
        #pragma unroll
        for (int s = 0; s < 2; ++s) {
            int id = tid + s * 256;
            aPl[s] = id >> 8; int rem = id & 255;
            aM[s] = rem >> 3; aK8[s] = (rem & 7) * 8;
        }
        const int kb = (tid >> 4) * 4;
        const int nb = (tid & 15) * 8;
        const int nchunk = (n0 + nb) >> 4;
        const int nshift = nb & 15;

        f32x4 acc[2][2] = {};
        uchar8v aReg[2];
        unsigned short bBits[4];

        auto loadA = [&](int k0) {
            #pragma unroll
            for (int s = 0; s < 2; ++s)
                aReg[s] = *(const uchar8v*)(W2p8 + (long long)aPl[s] * 16384 +
                                            (long long)aM[s] * 512 + k0 + aK8[s]);
        };
        auto loadB = [&](int k0) {
            unsigned long long u = *(const unsigned long long*)
                (Bb + (long long)nchunk * 512 + k0 + kb);
            bBits[0] = (unsigned short)u;
            bBits[1] = (unsigned short)(u >> 16);
            bBits[2] = (unsigned short)(u >> 32);
            bBits[3] = (unsigned short)(u >> 48);
        };
        auto stage = [&](int buf) {
            #pragma unroll
            for (int s = 0; s < 2; ++s) *(uchar8v*)&As[buf][aPl[s]][aM[s]][aK8[s]] = aReg[s];
            unsigned char bv[4][8];
            #pragma unroll
            for (int kk2 = 0; kk2 < 4; ++kk2) {
                unsigned int bits = ((unsigned int)bBits[kk2] >> nshift) & 0xFFu;
                #pragma unroll
                for (int j = 0; j < 8; ++j)
                    bv[kk2][j] = ((bits >> j) & 1u) ? ONE8 : (unsigned char)0;
            }
            #pragma unroll
            for (int j = 0; j < 8; ++j) {
                uchar4v v4 = { bv[0][j], bv[1][j], bv[2][j], bv[3][j] };
                *(uchar4v*)&Bs[buf][nb + j][kb] = v4;
            }
        };

        loadA(0); loadB(0);
        stage(0);
        __syncthreads();

        #pragma unroll
        for (int it = 0; it < 8; ++it) {
            const int cur = it & 1;
            const int kn = (it + 1) * 64;
            if (it < 7) { loadA(kn); loadB(kn); }

            #pragma unroll
            for (int ks = 0; ks < 2; ++ks) {
                i64 bfr[2];
                #pragma unroll
                for (int nt = 0; nt < 2; ++nt)
                    bfr[nt] = *(const i64*)&Bs[cur][w * 32 + nt * 16 + l15][ks * 32 + kq * 8];
                #pragma unroll
                for (int pl = 0; pl < 2; ++pl) {
                    #pragma unroll
                    for (int mt = 0; mt < 2; ++mt) {
                        i64 afr = *(const i64*)&As[cur][pl][mt * 16 + l15][ks * 32 + kq * 8];
                        #pragma unroll
                        for (int nt = 0; nt < 2; ++nt)
                            acc[mt][nt] = __builtin_amdgcn_mfma_f32_16x16x32_fp8_fp8(
                                afr, bfr[nt], acc[mt][nt], 0, 0, 0);
                    }
                }
            }

            if (it < 7) stage(cur ^ 1);
            __syncthreads();
        }

        float* Cb = C2p + (long long)b * 20 * 2048;
        #pragma unroll
        for (int mt = 0; mt < 2; ++mt) {
            #pragma unroll
            for (int i = 0; i < 4; ++i) {
                int m = mt * 16 + kq * 4 + i;
                if (m >= 20) continue;
                #pragma unroll
                for (int nt = 0; nt < 2; ++nt) {
                    int n = n0 + w * 32 + nt * 16 + l15;
                    Cb[(long long)m * 2048 + n] = acc[mt][nt][i];
                }
            }
        }
    } else {
        auto Xs = (float (*)[32])SMEM;              // [156][32]
        int* p  = (int*)(SMEM + 19968);             // [156]

        const int r0 = bx * 32;
        for (int i = tid; i < 156; i += 256) p[i] = perm[i];

        const int row = tid & 31;
        const int cq  = tid >> 5;
        #pragma unroll
        for (int it = 0; it < 20; ++it) {
            int c = it * 8 + cq;
            if (c < 156) {
                long long base = (long long)c * 16384 + r0 + row;
                float s = bf2f(Zp[base]) + bf2f(Zp[base + 2555904]) +
                          bf2f(Zp[base + 2 * 2555904]) + bf2f(Zp[base + 3 * 2555904]);
                Xs[c][row] = s;
            }
        }
        __syncthreads();

        if (tid < 32) {
            float y = 0.f;
            for (int c = 0; c < 156; ++c) {
                y = ALPHA * y + Xs[p[c]][tid];
                L1T[(long long)c * 16384 + r0 + tid] = (y >= THETA) ? BF1 : 0;
            }
        }
    }
}

// ---------------------------------------------------------------------------
// MEGA3: blocks [0,32)   = branch-2 GEMM2 + fused out-scan — FIRST (LPT)
//        blocks [32,672) = branch-1 final T-scan (shuffle scan)  (r9)
// ---------------------------------------------------------------------------
__global__ __launch_bounds__(256) void mega_stage3(
    const float* __restrict__ C2p, float* __restrict__ out,
    const unsigned short* __restrict__ Wl2p,
    const unsigned short* __restrict__ L1T)
{
    __shared__ alignas(16) unsigned char SMEM[36864];
    const int bx  = blockIdx.x;
    const int tid = threadIdx.x;

    if (bx >= 32) {
        const int row = bx - 32;
        const float* x = C2p + (long long)row * 2048 + tid * 8;

        float v[8];
        *(f32x4v*)&v[0] = *(const f32x4v*)x;
        *(f32x4v*)&v[4] = *(const f32x4v*)(x + 4);

        float y = 0.f;
        #pragma unroll
        for (int k = 0; k < 8; ++k) { y = ALPHA * y + v[k]; v[k] = y; }

        const int lane = tid & 63, wid = tid >> 6;
        float val = y, mm = ALPHA8;
        #pragma unroll
        for (int d = 1; d < 64; d <<= 1) {
            float p = __shfl_up(val, d);
            if (lane >= d) val += mm * p;
            mm *= mm;
        }
        float* wsum = (float*)SMEM;
        if (lane == 63) wsum[wid] = val;
        __syncthreads();
        float pw = 0.f;
        #pragma unroll
        for (int w2 = 0; w2 < 3; ++w2)
            if (w2 < wid) pw = pw * A64C + wsum[w2];
        float prev = __shfl_up(val, 1);
        float a8l  = __expf(-0.8f * (float)lane);
        float carry = (lane == 0) ? pw : (prev + a8l * pw);

        float* o = out + (long long)row * 2204 + tid * 8;
        float ak = ALPHA;
        #pragma unroll
        for (int k = 0; k < 8; ++k) {
            float yk = v[k] + ak * carry;
            ak *= ALPHA;
            o[k] = (yk >= THETA) ? 1.0f : 0.0f;
        }
    } else {
        auto As = (unsigned short (*)[32][72])SMEM;         // [2][32][72] : 9216 B
        auto Bs = (unsigned short (*)[72])(SMEM + 9216);    // [192][72]  : 27648 B

        const int b  = bx;
        const int lane = tid & 63, w = tid >> 6;
        const int l15 = lane & 15, kq = lane >> 4;

        f32x4 acc[2][3] = {};

        for (int k0 = 0; k0 < 512; k0 += 64) {
            #pragma unroll
            for (int s = 0; s < 2; ++s) {
                int id = tid + s * 256;
                int pl = id >> 8, rem = id & 255;
                int m = rem >> 3, k8 = (rem & 7) * 8;
                ushort8v v = *(const ushort8v*)(Wl2p + (long long)pl * 16384 +
                                                (long long)m * 512 + k0 + k8);
                *(ushort8v*)&As[pl][m][k8] = v;
            }
            #pragma unroll
            for (int s = 0; s < 6; ++s) {
                int id = tid + s * 256;
                int n = id >> 3, k8 = (id & 7) * 8;
                ushort8v v = {0,0,0,0,0,0,0,0};
                if (n < 156)
                    v = *(const ushort8v*)(L1T + (long long)n * 16384 +
                                           b * 512 + k0 + k8);
                *(ushort8v*)&Bs[n][k8] = v;
            }
            __syncthreads();

            #pragma unroll
            for (int ks = 0; ks < 2; ++ks) {
                bf16x8 bfr[3];
                #pragma unroll
                for (int nt = 0; nt < 3; ++nt)
                    bfr[nt] = *(const bf16x8*)&Bs[w * 48 + nt * 16 + l15][ks * 32 + kq * 8];
                #pragma unroll
                for (int s = 0; s < 2; ++s) {
                    #pragma unroll
                    for (int mt = 0; mt < 2; ++mt) {
                        bf16x8 afr = *(const bf16x8*)&As[s][mt * 16 + l15][ks * 32 + kq * 8];
                        #pragma unroll
                        for (int nt = 0; nt < 3; ++nt)
                            acc[mt][nt] = __builtin_amdgcn_mfma_f32_16x16x32_bf16(
                                afr, bfr[nt], acc[mt][nt], 0, 0, 0);
                    }
                }
            }
            __syncthreads();
        }

        float* Cs = (float*)SMEM;                   // [32][193] = 24704 B
        #pragma unroll
        for (int mt = 0; mt < 2; ++mt) {
            #pragma unroll
            for (int i = 0; i < 4; ++i) {
                int m = mt * 16 + kq * 4 + i;
                #pragma unroll
                for (int nt = 0; nt < 3; ++nt) {
                    int n = w * 48 + nt * 16 + l15;
                    Cs[m * 193 + n] = acc[mt][nt][i];
                }
            }
        }
        __syncthreads();

        if (tid < 20) {
            const float* cr = Cs + tid * 193;
            float* o = out + (long long)(b * 20 + tid) * 2204 + 2048;
            float y = 0.f;
            for (int c = 0; c < 156; ++c) {
                y = ALPHA * y + cr[c];
                o[c] = (y >= THETA) ? 1.0f : 0.0f;
            }
        }
    }
}

// ---------------------------------------------------------------------------
// B=32, C_IN=156, T=2048, HID=512, OUT=20. Output [32,20,2204].
// ---------------------------------------------------------------------------
extern "C" void kernel_launch(void* const* d_in, const int* in_sizes, int n_in,
                              void* d_out, int out_size, void* d_ws, size_t ws_size,
                              hipStream_t stream)
{
    const float* In  = (const float*)d_in[0];  // [32][156][2048]
    const float* W1  = (const float*)d_in[1];  // [512][156]
    const float* W2  = (const float*)d_in[2];  // [20][512]
    const float* Wl1 = (const float*)d_in[3];  // [512][2048]
    const float* Wl2 = (const float*)d_in[4];  // [20][512]
    const int*  perm = (const int*)d_in[5];    // [156]
    float* out = (float*)d_out;                // [32][20][2204]

    float* ws = (float*)d_ws;
    // Disjoint layout (float offsets; ws is 256 MiB):
    unsigned short* S1bits = (unsigned short*)ws;              // [32][128][512]
    float* C2p = ws + 1048576LL;                               // [32][20][2048] final
    unsigned char*  Infp8 = (unsigned char*)(ws + 3670016LL);  // [4992][2048] fp8
    unsigned short* Pbf  = (unsigned short*)(ws + 6225920LL);  // [32][160][2048] bf16
    unsigned short* W1p  = (unsigned short*)(ws + 16580608LL); // [2][512][160]
    unsigned char*  W2p8 = (unsigned char*)(ws + 16662528LL);  // [2][32][512] fp8
    unsigned char*  Wl1p8= (unsigned char*)(ws + 16670720LL);  // [2][512][2048] fp8
    unsigned short* Wl2p = (unsigned short*)(ws + 17195008LL); // [2][32][512]
    unsigned short* Zpbf = (unsigned short*)(ws + 17211392LL); // [4][156][16384] bf16
    unsigned short* L1T  = (unsigned short*)(ws + 22323200LL); // [156][16384]

    dim3 blk(256);

    // ---- Preprocess (fused scan + pack; Pbf padded to 160 c-rows) ----
    prep_scan_pack<<<dim3(6208), blk, 0, stream>>>(
        In, Infp8, Pbf, W1, W2, Wl1, Wl2, W1p, W2p8, Wl1p8, Wl2p);

    // ---- Stage 1: both branch GEMM1s (branch-2 first, LPT); B from Pbf ----
    mega_gemm1<<<dim3(3328), blk, 0, stream>>>(W1p, Pbf, S1bits,
                                               Wl1p8, Infp8, Zpbf);
    // ---- Stage 2: branch-2 perm-scan first, then branch-1 GEMM2 (full-K) ----
    mega_stage2<<<dim3(1024), blk, 0, stream>>>(W2p8, S1bits, C2p,
                                                Zpbf, perm, L1T);
    // ---- Stage 3: branch-2 GEMM2 (+fused out scan) first, then T-scans ----
    mega_stage3<<<dim3(672), blk, 0, stream>>>(C2p, out, Wl2p, L1T);

    (void)in_sizes; (void)n_in; (void)out_size; (void)ws_size;
}

// Round 11
// 173.934 us; speedup vs baseline: 1.0146x; 1.0146x over previous
//
#include <hip/hip_runtime.h>

// SLAYER constants
#define ALPHA  0.90483741803595952f   /* exp(-1/10) */
#define ALPHA8 0.44932896411722156f   /* exp(-0.8)  */
#define A64C   5.82e-23f              /* ALPHA8^64 = exp(-51.2), negligible tail */
#define THETA  10.0f
#define BF1    ((unsigned short)0x3F80) /* 1.0f as bf16 */
#define ISCALE 0.015625f               /* 1/64, exact */

typedef short   bf16x8 __attribute__((ext_vector_type(8)));
typedef float   f32x4  __attribute__((ext_vector_type(4)));
typedef float   f32x4v __attribute__((ext_vector_type(4)));
typedef unsigned short ushort4v __attribute__((ext_vector_type(4)));
typedef unsigned short ushort8v __attribute__((ext_vector_type(8)));
typedef unsigned char  uchar4v  __attribute__((ext_vector_type(4)));
typedef unsigned char  uchar8v  __attribute__((ext_vector_type(8)));
typedef long long i64;

// async global->LDS DMA, 16 B per lane. LDS dest = wave-uniform base + lane*16
#define DMA16(gsrc, ldst)                                                     \
    __builtin_amdgcn_global_load_lds(                                         \
        (const __attribute__((address_space(1))) unsigned int*)(gsrc),        \
        (__attribute__((address_space(3))) unsigned int*)(ldst), 16, 0, 0)

// HW transpose-read: 4x16 bf16 subtile, lane l elem j <- lds[(l&15)*2 + j*32
// + (l>>4)*128 + vaddr].  AS3 pointer (32-bit) as vaddr.
__device__ __forceinline__ i64 tr16(const unsigned char* p) {
    i64 r;
    asm volatile("ds_read_b64_tr_b16 %0, %1"
                 : "=v"(r)
                 : "v"((const __attribute__((address_space(3))) unsigned char*)p));
    return r;
}

// RNE float -> bf16 bits
__device__ __forceinline__ unsigned short f2bf(float f) {
    unsigned int x = __float_as_uint(f);
    unsigned int r = (x + 0x7FFFu + ((x >> 16) & 1u)) >> 16;
    return (unsigned short)r;
}
__device__ __forceinline__ float bf2f(unsigned short h) {
    return __uint_as_float(((unsigned int)h) << 16);
}
// 2-way bf16 split: w ~= h0+h1 (residual ~2^-17 rel)
__device__ __forceinline__ void split2(float w, unsigned short& h0,
                                       unsigned short& h1) {
    h0 = f2bf(w);          float r0 = w - bf2f(h0);
    h1 = f2bf(r0);
}
// HW fp8 converts
__device__ __forceinline__ unsigned char f2fp8(float f) {
    int pk = __builtin_amdgcn_cvt_pk_fp8_f32(f, 0.f, 0, false);
    return (unsigned char)(pk & 0xFF);
}
__device__ __forceinline__ float fp82f(unsigned char b) {
    return __builtin_amdgcn_cvt_f32_fp8((int)b, 0);
}

// ---------------------------------------------------------------------------
// prep_scan_pack: fused input prep + weight packing.  (r10, unchanged)
// Pbf is [32][160][2048] (c padded to 160 with ZERO rows).
// ---------------------------------------------------------------------------
__global__ __launch_bounds__(256) void prep_scan_pack(
    const float* __restrict__ In, unsigned char* __restrict__ Infp8,
    unsigned short* __restrict__ Pbf,
    const float* __restrict__ W1,  const float* __restrict__ W2,
    const float* __restrict__ Wl1, const float* __restrict__ Wl2,
    unsigned short* __restrict__ W1p,  unsigned char* __restrict__ W2p8,
    unsigned char* __restrict__ Wl1p8, unsigned short* __restrict__ Wl2p)
{
    const int blk = blockIdx.x;
    const int tid = threadIdx.x;
    if (blk >= 6080) {                          // Pbf zero-pad rows c=156..159
        int idx = blk - 6080;
        int b = idx >> 2, c = 156 + (idx & 3);
        ushort8v z = {0,0,0,0,0,0,0,0};
        *(ushort8v*)(Pbf + (long long)(b * 160 + c) * 2048 + tid * 8) = z;
        return;
    }
    if (blk < 1088) {
        if (blk < 512) {                            // Wl1 -> fp8 split-2, x64
            int m = blk;
            for (int k = tid; k < 2048; k += 256) {
                float w = Wl1[(long long)m * 2048 + k] * 64.0f;
                unsigned char h0 = f2fp8(w);
                unsigned char h1 = f2fp8(w - fp82f(h0));
                Wl1p8[(long long)m * 2048 + k] = h0;
                Wl1p8[1048576 + (long long)m * 2048 + k] = h1;
            }
        } else if (blk < 1024) {                    // W1 -> bf16 split-2
            int m = blk - 512;
            for (int k = tid; k < 160; k += 256) {
                float v = (k < 156) ? W1[(long long)m * 156 + k] : 0.f;
                unsigned short h0, h1;
                split2(v, h0, h1);
                W1p[(long long)m * 160 + k] = h0;
                W1p[81920 + (long long)m * 160 + k] = h1;
            }
        } else if (blk < 1056) {                    // W2 -> fp8 split-2
            int m = blk - 1024;
            for (int k = tid; k < 512; k += 256) {
                float w = (m < 20) ? W2[(long long)m * 512 + k] : 0.f;
                unsigned char h0 = f2fp8(w);
                unsigned char h1 = f2fp8(w - fp82f(h0));
                W2p8[(long long)m * 512 + k] = h0;
                W2p8[16384 + (long long)m * 512 + k] = h1;
            }
        } else {                                    // Wl2 -> bf16 split-2
            int m = blk - 1056;
            for (int k = tid; k < 512; k += 256) {
                float v = (m < 20) ? Wl2[(long long)m * 512 + k] : 0.f;
                unsigned short h0, h1;
                split2(v, h0, h1);
                Wl2p[(long long)m * 512 + k] = h0;
                Wl2p[16384 + (long long)m * 512 + k] = h1;
            }
        }
        return;
    }

    const int row = blk - 1088;
    const int bN  = row / 156;
    const int prow = bN * 160 + (row - bN * 156);
    const float* x = In + (long long)row * 2048 + tid * 8;
    const unsigned char ONE8 = f2fp8(1.0f);

    float v[8];
    *(f32x4v*)&v[0] = *(const f32x4v*)x;
    *(f32x4v*)&v[4] = *(const f32x4v*)(x + 4);

    uchar8v raw;
    #pragma unroll
    for (int k = 0; k < 8; ++k) raw[k] = (v[k] >= 0.5f) ? ONE8 : (unsigned char)0;
    *(uchar8v*)(Infp8 + (long long)row * 2048 + tid * 8) = raw;

    float y = 0.f;
    #pragma unroll
    for (int k = 0; k < 8; ++k) { y = ALPHA * y + v[k]; v[k] = y; }

    const int lane = tid & 63, wid = tid >> 6;
    float val = y, mm = ALPHA8;
    #pragma unroll
    for (int d = 1; d < 64; d <<= 1) {
        float p = __shfl_up(val, d);
        if (lane >= d) val += mm * p;
        mm *= mm;
    }
    __shared__ float wsum[4];
    if (lane == 63) wsum[wid] = val;
    __syncthreads();
    float pw = 0.f;
    #pragma unroll
    for (int w2 = 0; w2 < 3; ++w2)
        if (w2 < wid) pw = pw * A64C + wsum[w2];
    float prev = __shfl_up(val, 1);
    float a8l  = __expf(-0.8f * (float)lane);
    float carry = (lane == 0) ? pw : (prev + a8l * pw);

    ushort8v pv;
    float ak = ALPHA;
    #pragma unroll
    for (int k = 0; k < 8; ++k) {
        float yk = v[k] + ak * carry;
        ak *= ALPHA;
        pv[k] = f2bf(yk);
    }
    *(ushort8v*)(Pbf + (long long)prow * 2048 + tid * 8) = pv;
}

// ---------------------------------------------------------------------------
// MEGA1: blocks [0,640)   = branch-2 GEMM1 (fp8, NOW 128x128 tile, split-K
//                           x4) — first (LPT).  Halves LDS fragment reads
//                           per MFMA (24/64 vs 24/32) and staged bytes -25%.
//        blocks [640,2688) = branch-1 GEMM1 (bf16, 128x128, tr16 B from Pbf)
// ---------------------------------------------------------------------------
__global__ __launch_bounds__(256) void mega_gemm1(
    const unsigned short* __restrict__ W1p,
    const unsigned short* __restrict__ Pbf,  // [32][160][2048] bf16
    unsigned short* __restrict__ S1bits,     // [32][128 nchunk][512 m]
    const unsigned char* __restrict__ Wl1p8, // [2][512][2048] fp8
    const unsigned char* __restrict__ Infp8, // [4992][2048] fp8
    unsigned short* __restrict__ Zp)         // [4][156][16384] c-major bf16
{
    __shared__ alignas(16) unsigned char SMEM[49152];
    const int bx  = blockIdx.x;
    const int tid = threadIdx.x;
    const int lane = tid & 63, w = tid >> 6;
    const int wy = w >> 1, wx = w & 1;
    const int l15 = lane & 15, kq = lane >> 4;
    const int key = (l15 >> 1) & 3;          // swizzle key (A-side)

    if (bx >= 640) {
        // ========== branch-1 GEMM1 (bf16, 128x128, DMA staging) ==========
        unsigned char* Ab = SMEM;                  // [2buf][2pl][128m][32k] 2x16384
        unsigned char* Bb = SMEM + 32768;          // [2buf] tr16-subtiled   2x8192

        const int id1 = bx - 640;
        const int z  = id1 >> 6;
        const int m0 = ((id1 >> 4) & 3) * 128;
        const int n0 = (id1 & 15) * 128;

        const unsigned short* gA[4]; int ldsA[4];
        #pragma unroll
        for (int s = 0; s < 4; ++s) {
            int id = tid + s * 256;
            int pl = id >> 9, m = (id >> 2) & 127, g = id & 3;
            int gs = g ^ ((m >> 1) & 3);
            gA[s] = W1p + (long long)pl * 81920 + (long long)(m0 + m) * 160 + gs * 8;
            ldsA[s] = id * 16;
        }
        // B source: lane id -> (c, t8) of the subtiled layout (dest = id*16)
        const unsigned short* gB[2];
        #pragma unroll
        for (int s = 0; s < 2; ++s) {
            int id = tid + s * 256;
            int c  = ((id >> 6) << 2) | ((id >> 1) & 3);
            int t8 = ((((id >> 3) & 7) << 1) | (id & 1)) << 3;
            gB[s] = Pbf + (long long)(z * 160 + c) * 2048 + n0 + t8;
        }

        auto dmaA = [&](int buf) {
            unsigned char* dst = Ab + buf * 16384;
            #pragma unroll
            for (int s = 0; s < 4; ++s) { DMA16(gA[s], dst + ldsA[s]); gA[s] += 32; }
        };
        auto dmaB = [&](int buf) {
            unsigned char* dst = Bb + buf * 8192;
            #pragma unroll
            for (int s = 0; s < 2; ++s) {
                DMA16(gB[s], dst + (tid + s * 256) * 16);
                gB[s] += 65536;                  // +32 c rows
            }
        };

        int aOff[2][4];
        #pragma unroll
        for (int pl = 0; pl < 2; ++pl)
            #pragma unroll
            for (int mt = 0; mt < 4; ++mt)
                aOff[pl][mt] = pl * 8192 + (wy * 64 + mt * 16 + l15) * 64 +
                               ((kq ^ key) * 16);
        // tr16 base: quarter skew kq*1920 (+ HW kq*128 = subtile stride 2048)
        const int bTr = wx * 512 + kq * 1920;

        f32x4 acc[4][4] = {};

        dmaA(0); dmaB(0);
        __syncthreads();

        #pragma unroll
        for (int it = 0; it < 5; ++it) {
            const int cur = it & 1;
            if (it < 4) { dmaA(cur ^ 1); dmaB(cur ^ 1); }

            const unsigned char* Ac = Ab + cur * 16384;
            const unsigned char* vB = Bb + cur * 8192 + bTr;
            bf16x8 bfr[4];
            #pragma unroll
            for (int nt = 0; nt < 4; ++nt) {
                union { i64 q[2]; bf16x8 v; } u;
                u.q[0] = tr16(vB + nt * 128);            // c = kq*8+0..3
                u.q[1] = tr16(vB + 1024 + nt * 128);     // c = kq*8+4..7
                bfr[nt] = u.v;
            }
            asm volatile("s_waitcnt lgkmcnt(0)" ::: "memory");
            __builtin_amdgcn_sched_barrier(0);

            #pragma unroll
            for (int pl = 0; pl < 2; ++pl) {
                #pragma unroll
                for (int mt = 0; mt < 4; ++mt) {
                    bf16x8 afr = *(const bf16x8*)(Ac + aOff[pl][mt]);
                    #pragma unroll
                    for (int nt = 0; nt < 4; ++nt)
                        acc[mt][nt] = __builtin_amdgcn_mfma_f32_16x16x32_bf16(
                            afr, bfr[nt], acc[mt][nt], 0, 0, 0);
                }
            }
            __syncthreads();
        }

        unsigned short* Db = S1bits + (long long)z * 512 * 128;
        #pragma unroll
        for (int mt = 0; mt < 4; ++mt) {
            #pragma unroll
            for (int i = 0; i < 4; ++i) {
                int m = m0 + wy * 64 + mt * 16 + kq * 4 + i;
                #pragma unroll
                for (int nt = 0; nt < 4; ++nt) {
                    unsigned long long mask = __ballot(acc[mt][nt][i] >= THETA);
                    if (l15 == 0) {
                        int nchunk = (n0 + wx * 64 + nt * 16) >> 4;
                        Db[(long long)nchunk * 512 + m] =
                            (unsigned short)((mask >> (kq * 16)) & 0xFFFFu);
                    }
                }
            }
        }
    } else {
        // ========== branch-2 GEMM1 (fp8, 128x128, DMA staging) ==========
        unsigned char* Ab = SMEM;                  // [2buf][2pl][128m][64k] 2x16384
        unsigned char* Bb = SMEM + 32768;          // [2buf][128n][64k]      2x8192

        const int id0 = bx;
        const int nIdx = id0 % 40;
        if (nIdx >= 39) return;
        const int rest = id0 / 40;                 // 0..15
        const int n0  = nIdx * 128;
        const int m0  = (rest & 3) * 128;
        const int ksl = rest >> 2;
        const int ks0 = ksl * 512;

        const unsigned char* gA8[4]; int ldsA8[4];
        #pragma unroll
        for (int s = 0; s < 4; ++s) {
            int id = tid + s * 256;
            int pl = id >> 9, m = (id >> 2) & 127, g = id & 3;
            int gs = g ^ ((m >> 1) & 3);
            gA8[s] = Wl1p8 + (long long)pl * 1048576 +
                     (long long)(m0 + m) * 2048 + ks0 + gs * 16;
            ldsA8[s] = id * 16;
        }
        const unsigned char* gB8[2]; int ldsB8[2];
        #pragma unroll
        for (int s = 0; s < 2; ++s) {
            int id = tid + s * 256;
            int n = id >> 2, g = id & 3;
            int gs = g ^ ((n >> 1) & 3);
            gB8[s] = Infp8 + (long long)(n0 + n) * 2048 + ks0 + gs * 16;
            ldsB8[s] = id * 16;
        }

        auto dmaA8 = [&](int buf) {
            unsigned char* dst = Ab + buf * 16384;
            #pragma unroll
            for (int s = 0; s < 4; ++s) { DMA16(gA8[s], dst + ldsA8[s]); gA8[s] += 64; }
        };
        auto dmaB8 = [&](int buf) {
            unsigned char* dst = Bb + buf * 8192;
            #pragma unroll
            for (int s = 0; s < 2; ++s) { DMA16(gB8[s], dst + ldsB8[s]); gB8[s] += 64; }
        };

        int aO8[2][4][2], bO8[4][2];
        #pragma unroll
        for (int ks = 0; ks < 2; ++ks) {
            const int gl = ks * 2 + (kq >> 1);
            const int sub = ((gl ^ key) * 16) + (kq & 1) * 8;
            #pragma unroll
            for (int pl = 0; pl < 2; ++pl)
                #pragma unroll
                for (int mt = 0; mt < 4; ++mt)
                    aO8[pl][mt][ks] = pl * 8192 +
                        (wy * 64 + mt * 16 + l15) * 64 + sub;
            #pragma unroll
            for (int nt = 0; nt < 4; ++nt)
                bO8[nt][ks] = (wx * 64 + nt * 16 + l15) * 64 + sub;
        }

        f32x4 acc[4][4] = {};

        dmaA8(0); dmaB8(0);
        __syncthreads();

        #pragma unroll
        for (int it = 0; it < 8; ++it) {
            const int cur = it & 1;
            if (it < 7) { dmaA8(cur ^ 1); dmaB8(cur ^ 1); }

            const unsigned char* Ac = Ab + cur * 16384;
            const unsigned char* Bc = Bb + cur * 8192;
            #pragma unroll
            for (int ks = 0; ks < 2; ++ks) {
                i64 bfr[4];
                #pragma unroll
                for (int nt = 0; nt < 4; ++nt)
                    bfr[nt] = *(const i64*)(Bc + bO8[nt][ks]);
                #pragma unroll
                for (int pl = 0; pl < 2; ++pl) {
                    #pragma unroll
                    for (int mt = 0; mt < 4; ++mt) {
                        i64 afr = *(const i64*)(Ac + aO8[pl][mt][ks]);
                        #pragma unroll
                        for (int nt = 0; nt < 4; ++nt)
                            acc[mt][nt] = __builtin_amdgcn_mfma_f32_16x16x32_fp8_fp8(
                                afr, bfr[nt], acc[mt][nt], 0, 0, 0);
                    }
                }
            }
            __syncthreads();
        }

        unsigned short* Tu = (unsigned short*)SMEM;   // [128][130] overlay
        #pragma unroll
        for (int mt = 0; mt < 4; ++mt) {
            #pragma unroll
            for (int i = 0; i < 4; ++i) {
                int mL = wy * 64 + mt * 16 + kq * 4 + i;
                #pragma unroll
                for (int nt = 0; nt < 4; ++nt) {
                    int nL = wx * 64 + nt * 16 + l15;
                    Tu[mL * 130 + nL] = f2bf(acc[mt][nt][i] * ISCALE);
                }
            }
        }
        __syncthreads();

        unsigned short* Zs = Zp + (long long)ksl * 2555904;
        #pragma unroll
        for (int s2 = 0; s2 < 64; ++s2) {
            int id = tid + s2 * 256;
            int cL = id >> 7;
            int mL = id & 127;
            int n = n0 + cL;
            int bb = n / 156, cc = n - bb * 156;
            Zs[(long long)cc * 16384 + bb * 512 + m0 + mL] = Tu[mL * 130 + cL];
        }
    }
}

// ---------------------------------------------------------------------------
// MEGA2: blocks [0,512)    = branch-2 scan_sum4_perm (LDS-staged) — first
//        blocks [512,1024) = branch-1 GEMM2 (fp8 MFMA, full K=512)  (r10)
// ---------------------------------------------------------------------------
__global__ __launch_bounds__(256) void mega_stage2(
    const unsigned char* __restrict__ W2p8,
    const unsigned short* __restrict__ S1bits,   // [32][128 nchunk][512 m]
    float* __restrict__ C2p,                     // [32][20][2048] final
    const unsigned short* __restrict__ Zp,
    const int* __restrict__ perm,
    unsigned short* __restrict__ L1T)
{
    __shared__ alignas(16) unsigned char SMEM[27648];
    const int bx  = blockIdx.x;
    const int tid = threadIdx.x;

    if (bx >= 512) {
        auto As = (unsigned char (*)[2][32][72])SMEM;         // [buf][pl][32][72] : 2x4608
        auto Bs = (unsigned char (*)[128][72])(SMEM + 9216);  // [buf][128][72]    : 2x9216

        const int bxg = bx - 512;
        const int lane = tid & 63, w = tid >> 6;
        const int l15 = lane & 15, kq = lane >> 4;
        const int n0  = (bxg & 15) * 128;
        const int b   = bxg >> 4;

        const unsigned short* Bb = S1bits + (long long)b * 512 * 128;
        const unsigned char ONE8 = f2fp8(1.0f);

        int aPl[2], aM[2], aK8[2];
        #pragma unroll
        for (int s = 0; s < 2; ++s) {
            int id = tid + s * 256;
            aPl[s] = id >> 8; int rem = id & 255;
            aM[s] = rem >> 3; aK8[s] = (rem & 7) * 8;
        }
        const int kb = (tid >> 4) * 4;
        const int nb = (tid & 15) * 8;
        const int nchunk = (n0 + nb) >> 4;
        const int nshift = nb & 15;

        f32x4 acc[2][2] = {};
        uchar8v aReg[2];
        unsigned short bBits[4];

        auto loadA = [&](int k0) {
            #pragma unroll
            for (int s = 0; s < 2; ++s)
                aReg[s] = *(const uchar8v*)(W2p8 + (long long)aPl[s] * 16384 +
                                            (long long)aM[s] * 512 + k0 + aK8[s]);
        };
        auto loadB = [&](int k0) {
            unsigned long long u = *(const unsigned long long*)
                (Bb + (long long)nchunk * 512 + k0 + kb);
            bBits[0] = (unsigned short)u;
            bBits[1] = (unsigned short)(u >> 16);
            bBits[2] = (unsigned short)(u >> 32);
            bBits[3] = (unsigned short)(u >> 48);
        };
        auto stage = [&](int buf) {
            #pragma unroll
            for (int s = 0; s < 2; ++s) *(uchar8v*)&As[buf][aPl[s]][aM[s]][aK8[s]] = aReg[s];
            unsigned char bv[4][8];
            #pragma unroll
            for (int kk2 = 0; kk2 < 4; ++kk2) {
                unsigned int bits = ((unsigned int)bBits[kk2] >> nshift) & 0xFFu;
                #pragma unroll
                for (int j = 0; j < 8; ++j)
                    bv[kk2][j] = ((bits >> j) & 1u) ? ONE8 : (unsigned char)0;
            }
            #pragma unroll
            for (int j = 0; j < 8; ++j) {
                uchar4v v4 = { bv[0][j], bv[1][j], bv[2][j], bv[3][j] };
                *(uchar4v*)&Bs[buf][nb + j][kb] = v4;
            }
        };

        loadA(0); loadB(0);
        stage(0);
        __syncthreads();

        #pragma unroll
        for (int it = 0; it < 8; ++it) {
            const int cur = it & 1;
            const int kn = (it + 1) * 64;
            if (it < 7) { loadA(kn); loadB(kn); }

            #pragma unroll
            for (int ks = 0; ks < 2; ++ks) {
                i64 bfr[2];
                #pragma unroll
                for (int nt = 0; nt < 2; ++nt)
                    bfr[nt] = *(const i64*)&Bs[cur][w * 32 + nt * 16 + l15][ks * 32 + kq * 8];
                #pragma unroll
                for (int pl = 0; pl < 2; ++pl) {
                    #pragma unroll
                    for (int mt = 0; mt < 2; ++mt) {
                        i64 afr = *(const i64*)&As[cur][pl][mt * 16 + l15][ks * 32 + kq * 8];
                        #pragma unroll
                        for (int nt = 0; nt < 2; ++nt)
                            acc[mt][nt] = __builtin_amdgcn_mfma_f32_16x16x32_fp8_fp8(
                                afr, bfr[nt], acc[mt][nt], 0, 0, 0);
                    }
                }
            }

            if (it < 7) stage(cur ^ 1);
            __syncthreads();
        }

        float* Cb = C2p + (long long)b * 20 * 2048;
        #pragma unroll
        for (int mt = 0; mt < 2; ++mt) {
            #pragma unroll
            for (int i = 0; i < 4; ++i) {
                int m = mt * 16 + kq * 4 + i;
                if (m >= 20) continue;
                #pragma unroll
                for (int nt = 0; nt < 2; ++nt) {
                    int n = n0 + w * 32 + nt * 16 + l15;
                    Cb[(long long)m * 2048 + n] = acc[mt][nt][i];
                }
            }
        }
    } else {
        auto Xs = (float (*)[32])SMEM;              // [156][32]
        int* p  = (int*)(SMEM + 19968);             // [156]

        const int r0 = bx * 32;
        for (int i = tid; i < 156; i += 256) p[i] = perm[i];

        const int row = tid & 31;
        const int cq  = tid >> 5;
        #pragma unroll
        for (int it = 0; it < 20; ++it) {
            int c = it * 8 + cq;
            if (c < 156) {
                long long base = (long long)c * 16384 + r0 + row;
                float s = bf2f(Zp[base]) + bf2f(Zp[base + 2555904]) +
                          bf2f(Zp[base + 2 * 2555904]) + bf2f(Zp[base + 3 * 2555904]);
                Xs[c][row] = s;
            }
        }
        __syncthreads();

        if (tid < 32) {
            float y = 0.f;
            for (int c = 0; c < 156; ++c) {
                y = ALPHA * y + Xs[p[c]][tid];
                L1T[(long long)c * 16384 + r0 + tid] = (y >= THETA) ? BF1 : 0;
            }
        }
    }
}

// ---------------------------------------------------------------------------
// MEGA3: blocks [0,32)   = branch-2 GEMM2 + fused out-scan — FIRST (LPT)
//        blocks [32,672) = branch-1 final T-scan (shuffle scan)  (r10)
// ---------------------------------------------------------------------------
__global__ __launch_bounds__(256) void mega_stage3(
    const float* __restrict__ C2p, float* __restrict__ out,
    const unsigned short* __restrict__ Wl2p,
    const unsigned short* __restrict__ L1T)
{
    __shared__ alignas(16) unsigned char SMEM[36864];
    const int bx  = blockIdx.x;
    const int tid = threadIdx.x;

    if (bx >= 32) {
        const int row = bx - 32;
        const float* x = C2p + (long long)row * 2048 + tid * 8;

        float v[8];
        *(f32x4v*)&v[0] = *(const f32x4v*)x;
        *(f32x4v*)&v[4] = *(const f32x4v*)(x + 4);

        float y = 0.f;
        #pragma unroll
        for (int k = 0; k < 8; ++k) { y = ALPHA * y + v[k]; v[k] = y; }

        const int lane = tid & 63, wid = tid >> 6;
        float val = y, mm = ALPHA8;
        #pragma unroll
        for (int d = 1; d < 64; d <<= 1) {
            float p = __shfl_up(val, d);
            if (lane >= d) val += mm * p;
            mm *= mm;
        }
        float* wsum = (float*)SMEM;
        if (lane == 63) wsum[wid] = val;
        __syncthreads();
        float pw = 0.f;
        #pragma unroll
        for (int w2 = 0; w2 < 3; ++w2)
            if (w2 < wid) pw = pw * A64C + wsum[w2];
        float prev = __shfl_up(val, 1);
        float a8l  = __expf(-0.8f * (float)lane);
        float carry = (lane == 0) ? pw : (prev + a8l * pw);

        float* o = out + (long long)row * 2204 + tid * 8;
        float ak = ALPHA;
        #pragma unroll
        for (int k = 0; k < 8; ++k) {
            float yk = v[k] + ak * carry;
            ak *= ALPHA;
            o[k] = (yk >= THETA) ? 1.0f : 0.0f;
        }
    } else {
        auto As = (unsigned short (*)[32][72])SMEM;         // [2][32][72] : 9216 B
        auto Bs = (unsigned short (*)[72])(SMEM + 9216);    // [192][72]  : 27648 B

        const int b  = bx;
        const int lane = tid & 63, w = tid >> 6;
        const int l15 = lane & 15, kq = lane >> 4;

        f32x4 acc[2][3] = {};

        for (int k0 = 0; k0 < 512; k0 += 64) {
            #pragma unroll
            for (int s = 0; s < 2; ++s) {
                int id = tid + s * 256;
                int pl = id >> 8, rem = id & 255;
                int m = rem >> 3, k8 = (rem & 7) * 8;
                ushort8v v = *(const ushort8v*)(Wl2p + (long long)pl * 16384 +
                                                (long long)m * 512 + k0 + k8);
                *(ushort8v*)&As[pl][m][k8] = v;
            }
            #pragma unroll
            for (int s = 0; s < 6; ++s) {
                int id = tid + s * 256;
                int n = id >> 3, k8 = (id & 7) * 8;
                ushort8v v = {0,0,0,0,0,0,0,0};
                if (n < 156)
                    v = *(const ushort8v*)(L1T + (long long)n * 16384 +
                                           b * 512 + k0 + k8);
                *(ushort8v*)&Bs[n][k8] = v;
            }
            __syncthreads();

            #pragma unroll
            for (int ks = 0; ks < 2; ++ks) {
                bf16x8 bfr[3];
                #pragma unroll
                for (int nt = 0; nt < 3; ++nt)
                    bfr[nt] = *(const bf16x8*)&Bs[w * 48 + nt * 16 + l15][ks * 32 + kq * 8];
                #pragma unroll
                for (int s = 0; s < 2; ++s) {
                    #pragma unroll
                    for (int mt = 0; mt < 2; ++mt) {
                        bf16x8 afr = *(const bf16x8*)&As[s][mt * 16 + l15][ks * 32 + kq * 8];
                        #pragma unroll
                        for (int nt = 0; nt < 3; ++nt)
                            acc[mt][nt] = __builtin_amdgcn_mfma_f32_16x16x32_bf16(
                                afr, bfr[nt], acc[mt][nt], 0, 0, 0);
                    }
                }
            }
            __syncthreads();
        }

        float* Cs = (float*)SMEM;                   // [32][193] = 24704 B
        #pragma unroll
        for (int mt = 0; mt < 2; ++mt) {
            #pragma unroll
            for (int i = 0; i < 4; ++i) {
                int m = mt * 16 + kq * 4 + i;
                #pragma unroll
                for (int nt = 0; nt < 3; ++nt) {
                    int n = w * 48 + nt * 16 + l15;
                    Cs[m * 193 + n] = acc[mt][nt][i];
                }
            }
        }
        __syncthreads();

        if (tid < 20) {
            const float* cr = Cs + tid * 193;
            float* o = out + (long long)(b * 20 + tid) * 2204 + 2048;
            float y = 0.f;
            for (int c = 0; c < 156; ++c) {
                y = ALPHA * y + cr[c];
                o[c] = (y >= THETA) ? 1.0f : 0.0f;
            }
        }
    }
}

// ---------------------------------------------------------------------------
// B=32, C_IN=156, T=2048, HID=512, OUT=20. Output [32,20,2204].
// ---------------------------------------------------------------------------
extern "C" void kernel_launch(void* const* d_in, const int* in_sizes, int n_in,
                              void* d_out, int out_size, void* d_ws, size_t ws_size,
                              hipStream_t stream)
{
    const float* In  = (const float*)d_in[0];  // [32][156][2048]
    const float* W1  = (const float*)d_in[1];  // [512][156]
    const float* W2  = (const float*)d_in[2];  // [20][512]
    const float* Wl1 = (const float*)d_in[3];  // [512][2048]
    const float* Wl2 = (const float*)d_in[4];  // [20][512]
    const int*  perm = (const int*)d_in[5];    // [156]
    float* out = (float*)d_out;                // [32][20][2204]

    float* ws = (float*)d_ws;
    // Disjoint layout (float offsets; ws is 256 MiB):
    unsigned short* S1bits = (unsigned short*)ws;              // [32][128][512]
    float* C2p = ws + 1048576LL;                               // [32][20][2048] final
    unsigned char*  Infp8 = (unsigned char*)(ws + 3670016LL);  // [4992][2048] fp8
    unsigned short* Pbf  = (unsigned short*)(ws + 6225920LL);  // [32][160][2048] bf16
    unsigned short* W1p  = (unsigned short*)(ws + 16580608LL); // [2][512][160]
    unsigned char*  W2p8 = (unsigned char*)(ws + 16662528LL);  // [2][32][512] fp8
    unsigned char*  Wl1p8= (unsigned char*)(ws + 16670720LL);  // [2][512][2048] fp8
    unsigned short* Wl2p = (unsigned short*)(ws + 17195008LL); // [2][32][512]
    unsigned short* Zpbf = (unsigned short*)(ws + 17211392LL); // [4][156][16384] bf16
    unsigned short* L1T  = (unsigned short*)(ws + 22323200LL); // [156][16384]

    dim3 blk(256);

    // ---- Preprocess (fused scan + pack; Pbf padded to 160 c-rows) ----
    prep_scan_pack<<<dim3(6208), blk, 0, stream>>>(
        In, Infp8, Pbf, W1, W2, Wl1, Wl2, W1p, W2p8, Wl1p8, Wl2p);

    // ---- Stage 1: both branch GEMM1s (branch-2 128x128 first, LPT) ----
    mega_gemm1<<<dim3(2688), blk, 0, stream>>>(W1p, Pbf, S1bits,
                                               Wl1p8, Infp8, Zpbf);
    // ---- Stage 2: branch-2 perm-scan first, then branch-1 GEMM2 (full-K) ----
    mega_stage2<<<dim3(1024), blk, 0, stream>>>(W2p8, S1bits, C2p,
                                                Zpbf, perm, L1T);
    // ---- Stage 3: branch-2 GEMM2 (+fused out scan) first, then T-scans ----
    mega_stage3<<<dim3(672), blk, 0, stream>>>(C2p, out, Wl2p, L1T);

    (void)in_sizes; (void)n_in; (void)out_size; (void)ws_size;
}

// Round 12
// 172.680 us; speedup vs baseline: 1.0220x; 1.0073x over previous
//
#include <hip/hip_runtime.h>

// SLAYER constants
#define ALPHA  0.90483741803595952f   /* exp(-1/10) */
#define ALPHA8 0.44932896411722156f   /* exp(-0.8)  */
#define A64C   5.82e-23f              /* ALPHA8^64 = exp(-51.2), negligible tail */
#define THETA  10.0f
#define BF1    ((unsigned short)0x3F80) /* 1.0f as bf16 */
#define ISCALE 0.015625f               /* 1/64, exact */

typedef short   bf16x8 __attribute__((ext_vector_type(8)));
typedef float   f32x4  __attribute__((ext_vector_type(4)));
typedef float   f32x4v __attribute__((ext_vector_type(4)));
typedef unsigned short ushort4v __attribute__((ext_vector_type(4)));
typedef unsigned short ushort8v __attribute__((ext_vector_type(8)));
typedef unsigned char  uchar4v  __attribute__((ext_vector_type(4)));
typedef unsigned char  uchar8v  __attribute__((ext_vector_type(8)));
typedef long long i64;

// async global->LDS DMA, 16 B per lane. LDS dest = wave-uniform base + lane*16
#define DMA16(gsrc, ldst)                                                     \
    __builtin_amdgcn_global_load_lds(                                         \
        (const __attribute__((address_space(1))) unsigned int*)(gsrc),        \
        (__attribute__((address_space(3))) unsigned int*)(ldst), 16, 0, 0)

// HW transpose-read: 4x16 bf16 subtile, lane l elem j <- lds[(l&15)*2 + j*32
// + (l>>4)*128 + vaddr].  AS3 pointer (32-bit) as vaddr.
__device__ __forceinline__ i64 tr16(const unsigned char* p) {
    i64 r;
    asm volatile("ds_read_b64_tr_b16 %0, %1"
                 : "=v"(r)
                 : "v"((const __attribute__((address_space(3))) unsigned char*)p));
    return r;
}

// RNE float -> bf16 bits
__device__ __forceinline__ unsigned short f2bf(float f) {
    unsigned int x = __float_as_uint(f);
    unsigned int r = (x + 0x7FFFu + ((x >> 16) & 1u)) >> 16;
    return (unsigned short)r;
}
__device__ __forceinline__ float bf2f(unsigned short h) {
    return __uint_as_float(((unsigned int)h) << 16);
}
// 2-way bf16 split: w ~= h0+h1 (residual ~2^-17 rel)
__device__ __forceinline__ void split2(float w, unsigned short& h0,
                                       unsigned short& h1) {
    h0 = f2bf(w);          float r0 = w - bf2f(h0);
    h1 = f2bf(r0);
}
// HW fp8 converts
__device__ __forceinline__ unsigned char f2fp8(float f) {
    int pk = __builtin_amdgcn_cvt_pk_fp8_f32(f, 0.f, 0, false);
    return (unsigned char)(pk & 0xFF);
}
__device__ __forceinline__ float fp82f(unsigned char b) {
    return __builtin_amdgcn_cvt_f32_fp8((int)b, 0);
}

// ---------------------------------------------------------------------------
// prep_scan_pack: fused input prep + weight packing.  (r11, unchanged)
// Pbf is [32][160][2048] (c padded to 160 with ZERO rows).
// ---------------------------------------------------------------------------
__global__ __launch_bounds__(256) void prep_scan_pack(
    const float* __restrict__ In, unsigned char* __restrict__ Infp8,
    unsigned short* __restrict__ Pbf,
    const float* __restrict__ W1,  const float* __restrict__ W2,
    const float* __restrict__ Wl1, const float* __restrict__ Wl2,
    unsigned short* __restrict__ W1p,  unsigned char* __restrict__ W2p8,
    unsigned char* __restrict__ Wl1p8, unsigned short* __restrict__ Wl2p)
{
    const int blk = blockIdx.x;
    const int tid = threadIdx.x;
    if (blk >= 6080) {                          // Pbf zero-pad rows c=156..159
        int idx = blk - 6080;
        int b = idx >> 2, c = 156 + (idx & 3);
        ushort8v z = {0,0,0,0,0,0,0,0};
        *(ushort8v*)(Pbf + (long long)(b * 160 + c) * 2048 + tid * 8) = z;
        return;
    }
    if (blk < 1088) {
        if (blk < 512) {                            // Wl1 -> fp8 split-2, x64
            int m = blk;
            for (int k = tid; k < 2048; k += 256) {
                float w = Wl1[(long long)m * 2048 + k] * 64.0f;
                unsigned char h0 = f2fp8(w);
                unsigned char h1 = f2fp8(w - fp82f(h0));
                Wl1p8[(long long)m * 2048 + k] = h0;
                Wl1p8[1048576 + (long long)m * 2048 + k] = h1;
            }
        } else if (blk < 1024) {                    // W1 -> bf16 split-2
            int m = blk - 512;
            for (int k = tid; k < 160; k += 256) {
                float v = (k < 156) ? W1[(long long)m * 156 + k] : 0.f;
                unsigned short h0, h1;
                split2(v, h0, h1);
                W1p[(long long)m * 160 + k] = h0;
                W1p[81920 + (long long)m * 160 + k] = h1;
            }
        } else if (blk < 1056) {                    // W2 -> fp8 split-2
            int m = blk - 1024;
            for (int k = tid; k < 512; k += 256) {
                float w = (m < 20) ? W2[(long long)m * 512 + k] : 0.f;
                unsigned char h0 = f2fp8(w);
                unsigned char h1 = f2fp8(w - fp82f(h0));
                W2p8[(long long)m * 512 + k] = h0;
                W2p8[16384 + (long long)m * 512 + k] = h1;
            }
        } else {                                    // Wl2 -> bf16 split-2
            int m = blk - 1056;
            for (int k = tid; k < 512; k += 256) {
                float v = (m < 20) ? Wl2[(long long)m * 512 + k] : 0.f;
                unsigned short h0, h1;
                split2(v, h0, h1);
                Wl2p[(long long)m * 512 + k] = h0;
                Wl2p[16384 + (long long)m * 512 + k] = h1;
            }
        }
        return;
    }

    const int row = blk - 1088;
    const int bN  = row / 156;
    const int prow = bN * 160 + (row - bN * 156);
    const float* x = In + (long long)row * 2048 + tid * 8;
    const unsigned char ONE8 = f2fp8(1.0f);

    float v[8];
    *(f32x4v*)&v[0] = *(const f32x4v*)x;
    *(f32x4v*)&v[4] = *(const f32x4v*)(x + 4);

    uchar8v raw;
    #pragma unroll
    for (int k = 0; k < 8; ++k) raw[k] = (v[k] >= 0.5f) ? ONE8 : (unsigned char)0;
    *(uchar8v*)(Infp8 + (long long)row * 2048 + tid * 8) = raw;

    float y = 0.f;
    #pragma unroll
    for (int k = 0; k < 8; ++k) { y = ALPHA * y + v[k]; v[k] = y; }

    const int lane = tid & 63, wid = tid >> 6;
    float val = y, mm = ALPHA8;
    #pragma unroll
    for (int d = 1; d < 64; d <<= 1) {
        float p = __shfl_up(val, d);
        if (lane >= d) val += mm * p;
        mm *= mm;
    }
    __shared__ float wsum[4];
    if (lane == 63) wsum[wid] = val;
    __syncthreads();
    float pw = 0.f;
    #pragma unroll
    for (int w2 = 0; w2 < 3; ++w2)
        if (w2 < wid) pw = pw * A64C + wsum[w2];
    float prev = __shfl_up(val, 1);
    float a8l  = __expf(-0.8f * (float)lane);
    float carry = (lane == 0) ? pw : (prev + a8l * pw);

    ushort8v pv;
    float ak = ALPHA;
    #pragma unroll
    for (int k = 0; k < 8; ++k) {
        float yk = v[k] + ak * carry;
        ak *= ALPHA;
        pv[k] = f2bf(yk);
    }
    *(ushort8v*)(Pbf + (long long)prow * 2048 + tid * 8) = pv;
}

// ---------------------------------------------------------------------------
// MEGA1: blocks [0,320)   = branch-2 GEMM1 (fp8, 128x128 tile, split-K x2:
//                           K=1024/block, 16 K-steps) — first (LPT).
//                           Zp shrinks to 2 planes (-20 MB traffic), half
//                           the epilogue executions, deeper dbuf pipeline.
//        blocks [320,2368) = branch-1 GEMM1 (bf16, 128x128, tr16 B from Pbf)
// ---------------------------------------------------------------------------
__global__ __launch_bounds__(256) void mega_gemm1(
    const unsigned short* __restrict__ W1p,
    const unsigned short* __restrict__ Pbf,  // [32][160][2048] bf16
    unsigned short* __restrict__ S1bits,     // [32][128 nchunk][512 m]
    const unsigned char* __restrict__ Wl1p8, // [2][512][2048] fp8
    const unsigned char* __restrict__ Infp8, // [4992][2048] fp8
    unsigned short* __restrict__ Zp)         // [2][156][16384] c-major bf16
{
    __shared__ alignas(16) unsigned char SMEM[49152];
    const int bx  = blockIdx.x;
    const int tid = threadIdx.x;
    const int lane = tid & 63, w = tid >> 6;
    const int wy = w >> 1, wx = w & 1;
    const int l15 = lane & 15, kq = lane >> 4;
    const int key = (l15 >> 1) & 3;          // swizzle key (A-side)

    if (bx >= 320) {
        // ========== branch-1 GEMM1 (bf16, 128x128, DMA staging) ==========
        unsigned char* Ab = SMEM;                  // [2buf][2pl][128m][32k] 2x16384
        unsigned char* Bb = SMEM + 32768;          // [2buf] tr16-subtiled   2x8192

        const int id1 = bx - 320;
        const int z  = id1 >> 6;
        const int m0 = ((id1 >> 4) & 3) * 128;
        const int n0 = (id1 & 15) * 128;

        const unsigned short* gA[4]; int ldsA[4];
        #pragma unroll
        for (int s = 0; s < 4; ++s) {
            int id = tid + s * 256;
            int pl = id >> 9, m = (id >> 2) & 127, g = id & 3;
            int gs = g ^ ((m >> 1) & 3);
            gA[s] = W1p + (long long)pl * 81920 + (long long)(m0 + m) * 160 + gs * 8;
            ldsA[s] = id * 16;
        }
        // B source: lane id -> (c, t8) of the subtiled layout (dest = id*16)
        const unsigned short* gB[2];
        #pragma unroll
        for (int s = 0; s < 2; ++s) {
            int id = tid + s * 256;
            int c  = ((id >> 6) << 2) | ((id >> 1) & 3);
            int t8 = ((((id >> 3) & 7) << 1) | (id & 1)) << 3;
            gB[s] = Pbf + (long long)(z * 160 + c) * 2048 + n0 + t8;
        }

        auto dmaA = [&](int buf) {
            unsigned char* dst = Ab + buf * 16384;
            #pragma unroll
            for (int s = 0; s < 4; ++s) { DMA16(gA[s], dst + ldsA[s]); gA[s] += 32; }
        };
        auto dmaB = [&](int buf) {
            unsigned char* dst = Bb + buf * 8192;
            #pragma unroll
            for (int s = 0; s < 2; ++s) {
                DMA16(gB[s], dst + (tid + s * 256) * 16);
                gB[s] += 65536;                  // +32 c rows
            }
        };

        int aOff[2][4];
        #pragma unroll
        for (int pl = 0; pl < 2; ++pl)
            #pragma unroll
            for (int mt = 0; mt < 4; ++mt)
                aOff[pl][mt] = pl * 8192 + (wy * 64 + mt * 16 + l15) * 64 +
                               ((kq ^ key) * 16);
        // tr16 base: quarter skew kq*1920 (+ HW kq*128 = subtile stride 2048)
        const int bTr = wx * 512 + kq * 1920;

        f32x4 acc[4][4] = {};

        dmaA(0); dmaB(0);
        __syncthreads();

        #pragma unroll
        for (int it = 0; it < 5; ++it) {
            const int cur = it & 1;
            if (it < 4) { dmaA(cur ^ 1); dmaB(cur ^ 1); }

            const unsigned char* Ac = Ab + cur * 16384;
            const unsigned char* vB = Bb + cur * 8192 + bTr;
            bf16x8 bfr[4];
            #pragma unroll
            for (int nt = 0; nt < 4; ++nt) {
                union { i64 q[2]; bf16x8 v; } u;
                u.q[0] = tr16(vB + nt * 128);            // c = kq*8+0..3
                u.q[1] = tr16(vB + 1024 + nt * 128);     // c = kq*8+4..7
                bfr[nt] = u.v;
            }
            asm volatile("s_waitcnt lgkmcnt(0)" ::: "memory");
            __builtin_amdgcn_sched_barrier(0);

            #pragma unroll
            for (int pl = 0; pl < 2; ++pl) {
                #pragma unroll
                for (int mt = 0; mt < 4; ++mt) {
                    bf16x8 afr = *(const bf16x8*)(Ac + aOff[pl][mt]);
                    #pragma unroll
                    for (int nt = 0; nt < 4; ++nt)
                        acc[mt][nt] = __builtin_amdgcn_mfma_f32_16x16x32_bf16(
                            afr, bfr[nt], acc[mt][nt], 0, 0, 0);
                }
            }
            __syncthreads();
        }

        unsigned short* Db = S1bits + (long long)z * 512 * 128;
        #pragma unroll
        for (int mt = 0; mt < 4; ++mt) {
            #pragma unroll
            for (int i = 0; i < 4; ++i) {
                int m = m0 + wy * 64 + mt * 16 + kq * 4 + i;
                #pragma unroll
                for (int nt = 0; nt < 4; ++nt) {
                    unsigned long long mask = __ballot(acc[mt][nt][i] >= THETA);
                    if (l15 == 0) {
                        int nchunk = (n0 + wx * 64 + nt * 16) >> 4;
                        Db[(long long)nchunk * 512 + m] =
                            (unsigned short)((mask >> (kq * 16)) & 0xFFFFu);
                    }
                }
            }
        }
    } else {
        // ========== branch-2 GEMM1 (fp8, 128x128, K=1024, DMA staging) =====
        unsigned char* Ab = SMEM;                  // [2buf][2pl][128m][64k] 2x16384
        unsigned char* Bb = SMEM + 32768;          // [2buf][128n][64k]      2x8192

        const int id0 = bx;
        const int nIdx = id0 % 40;
        if (nIdx >= 39) return;
        const int rest = id0 / 40;                 // 0..7
        const int n0  = nIdx * 128;
        const int m0  = (rest & 3) * 128;
        const int ksl = rest >> 2;                 // 0..1
        const int ks0 = ksl * 1024;

        const unsigned char* gA8[4]; int ldsA8[4];
        #pragma unroll
        for (int s = 0; s < 4; ++s) {
            int id = tid + s * 256;
            int pl = id >> 9, m = (id >> 2) & 127, g = id & 3;
            int gs = g ^ ((m >> 1) & 3);
            gA8[s] = Wl1p8 + (long long)pl * 1048576 +
                     (long long)(m0 + m) * 2048 + ks0 + gs * 16;
            ldsA8[s] = id * 16;
        }
        const unsigned char* gB8[2]; int ldsB8[2];
        #pragma unroll
        for (int s = 0; s < 2; ++s) {
            int id = tid + s * 256;
            int n = id >> 2, g = id & 3;
            int gs = g ^ ((n >> 1) & 3);
            gB8[s] = Infp8 + (long long)(n0 + n) * 2048 + ks0 + gs * 16;
            ldsB8[s] = id * 16;
        }

        auto dmaA8 = [&](int buf) {
            unsigned char* dst = Ab + buf * 16384;
            #pragma unroll
            for (int s = 0; s < 4; ++s) { DMA16(gA8[s], dst + ldsA8[s]); gA8[s] += 64; }
        };
        auto dmaB8 = [&](int buf) {
            unsigned char* dst = Bb + buf * 8192;
            #pragma unroll
            for (int s = 0; s < 2; ++s) { DMA16(gB8[s], dst + ldsB8[s]); gB8[s] += 64; }
        };

        int aO8[2][4][2], bO8[4][2];
        #pragma unroll
        for (int ks = 0; ks < 2; ++ks) {
            const int gl = ks * 2 + (kq >> 1);
            const int sub = ((gl ^ key) * 16) + (kq & 1) * 8;
            #pragma unroll
            for (int pl = 0; pl < 2; ++pl)
                #pragma unroll
                for (int mt = 0; mt < 4; ++mt)
                    aO8[pl][mt][ks] = pl * 8192 +
                        (wy * 64 + mt * 16 + l15) * 64 + sub;
            #pragma unroll
            for (int nt = 0; nt < 4; ++nt)
                bO8[nt][ks] = (wx * 64 + nt * 16 + l15) * 64 + sub;
        }

        f32x4 acc[4][4] = {};

        dmaA8(0); dmaB8(0);
        __syncthreads();

        for (int it = 0; it < 16; ++it) {
            const int cur = it & 1;
            if (it < 15) { dmaA8(cur ^ 1); dmaB8(cur ^ 1); }

            const unsigned char* Ac = Ab + cur * 16384;
            const unsigned char* Bc = Bb + cur * 8192;
            #pragma unroll
            for (int ks = 0; ks < 2; ++ks) {
                i64 bfr[4];
                #pragma unroll
                for (int nt = 0; nt < 4; ++nt)
                    bfr[nt] = *(const i64*)(Bc + bO8[nt][ks]);
                #pragma unroll
                for (int pl = 0; pl < 2; ++pl) {
                    #pragma unroll
                    for (int mt = 0; mt < 4; ++mt) {
                        i64 afr = *(const i64*)(Ac + aO8[pl][mt][ks]);
                        #pragma unroll
                        for (int nt = 0; nt < 4; ++nt)
                            acc[mt][nt] = __builtin_amdgcn_mfma_f32_16x16x32_fp8_fp8(
                                afr, bfr[nt], acc[mt][nt], 0, 0, 0);
                    }
                }
            }
            __syncthreads();
        }

        unsigned short* Tu = (unsigned short*)SMEM;   // [128][130] overlay
        #pragma unroll
        for (int mt = 0; mt < 4; ++mt) {
            #pragma unroll
            for (int i = 0; i < 4; ++i) {
                int mL = wy * 64 + mt * 16 + kq * 4 + i;
                #pragma unroll
                for (int nt = 0; nt < 4; ++nt) {
                    int nL = wx * 64 + nt * 16 + l15;
                    Tu[mL * 130 + nL] = f2bf(acc[mt][nt][i] * ISCALE);
                }
            }
        }
        __syncthreads();

        unsigned short* Zs = Zp + (long long)ksl * 2555904;
        #pragma unroll
        for (int s2 = 0; s2 < 64; ++s2) {
            int id = tid + s2 * 256;
            int cL = id >> 7;
            int mL = id & 127;
            int n = n0 + cL;
            int bb = n / 156, cc = n - bb * 156;
            Zs[(long long)cc * 16384 + bb * 512 + m0 + mL] = Tu[mL * 130 + cL];
        }
    }
}

// ---------------------------------------------------------------------------
// MEGA2: blocks [0,512)    = branch-2 scan_sum2_perm (LDS-staged) — first
//        blocks [512,1024) = branch-1 GEMM2 (fp8 MFMA, full K=512)  (r11)
// ---------------------------------------------------------------------------
__global__ __launch_bounds__(256) void mega_stage2(
    const unsigned char* __restrict__ W2p8,
    const unsigned short* __restrict__ S1bits,   // [32][128 nchunk][512 m]
    float* __restrict__ C2p,                     // [32][20][2048] final
    const unsigned short* __restrict__ Zp,       // [2][156][16384] bf16
    const int* __restrict__ perm,
    unsigned short* __restrict__ L1T)
{
    __shared__ alignas(16) unsigned char SMEM[27648];
    const int bx  = blockIdx.x;
    const int tid = threadIdx.x;

    if (bx >= 512) {
        auto As = (unsigned char (*)[2][32][72])SMEM;         // [buf][pl][32][72] : 2x4608
        auto Bs = (unsigned char (*)[128][72])(SMEM + 9216);  // [buf][128][72]    : 2x9216

        const int bxg = bx - 512;
        const int lane = tid & 63, w = tid >> 6;
        const int l15 = lane & 15, kq = lane >> 4;
        const int n0  = (bxg & 15) * 128;
        const int b   = bxg >> 4;

        const unsigned short* Bb = S1bits + (long long)b * 512 * 128;
        const unsigned char ONE8 = f2fp8(1.0f);

        int aPl[2], aM[2], aK8[2];
        #pragma unroll
        for (int s = 0; s < 2; ++s) {
            int id = tid + s * 256;
            aPl[s] = id >> 8; int rem = id & 255;
            aM[s] = rem >> 3; aK8[s] = (rem & 7) * 8;
        }
        const int kb = (tid >> 4) * 4;
        const int nb = (tid & 15) * 8;
        const int nchunk = (n0 + nb) >> 4;
        const int nshift = nb & 15;

        f32x4 acc[2][2] = {};
        uchar8v aReg[2];
        unsigned short bBits[4];

        auto loadA = [&](int k0) {
            #pragma unroll
            for (int s = 0; s < 2; ++s)
                aReg[s] = *(const uchar8v*)(W2p8 + (long long)aPl[s] * 16384 +
                                            (long long)aM[s] * 512 + k0 + aK8[s]);
        };
        auto loadB = [&](int k0) {
            unsigned long long u = *(const unsigned long long*)
                (Bb + (long long)nchunk * 512 + k0 + kb);
            bBits[0] = (unsigned short)u;
            bBits[1] = (unsigned short)(u >> 16);
            bBits[2] = (unsigned short)(u >> 32);
            bBits[3] = (unsigned short)(u >> 48);
        };
        auto stage = [&](int buf) {
            #pragma unroll
            for (int s = 0; s < 2; ++s) *(uchar8v*)&As[buf][aPl[s]][aM[s]][aK8[s]] = aReg[s];
            unsigned char bv[4][8];
            #pragma unroll
            for (int kk2 = 0; kk2 < 4; ++kk2) {
                unsigned int bits = ((unsigned int)bBits[kk2] >> nshift) & 0xFFu;
                #pragma unroll
                for (int j = 0; j < 8; ++j)
                    bv[kk2][j] = ((bits >> j) & 1u) ? ONE8 : (unsigned char)0;
            }
            #pragma unroll
            for (int j = 0; j < 8; ++j) {
                uchar4v v4 = { bv[0][j], bv[1][j], bv[2][j], bv[3][j] };
                *(uchar4v*)&Bs[buf][nb + j][kb] = v4;
            }
        };

        loadA(0); loadB(0);
        stage(0);
        __syncthreads();

        #pragma unroll
        for (int it = 0; it < 8; ++it) {
            const int cur = it & 1;
            const int kn = (it + 1) * 64;
            if (it < 7) { loadA(kn); loadB(kn); }

            #pragma unroll
            for (int ks = 0; ks < 2; ++ks) {
                i64 bfr[2];
                #pragma unroll
                for (int nt = 0; nt < 2; ++nt)
                    bfr[nt] = *(const i64*)&Bs[cur][w * 32 + nt * 16 + l15][ks * 32 + kq * 8];
                #pragma unroll
                for (int pl = 0; pl < 2; ++pl) {
                    #pragma unroll
                    for (int mt = 0; mt < 2; ++mt) {
                        i64 afr = *(const i64*)&As[cur][pl][mt * 16 + l15][ks * 32 + kq * 8];
                        #pragma unroll
                        for (int nt = 0; nt < 2; ++nt)
                            acc[mt][nt] = __builtin_amdgcn_mfma_f32_16x16x32_fp8_fp8(
                                afr, bfr[nt], acc[mt][nt], 0, 0, 0);
                    }
                }
            }

            if (it < 7) stage(cur ^ 1);
            __syncthreads();
        }

        float* Cb = C2p + (long long)b * 20 * 2048;
        #pragma unroll
        for (int mt = 0; mt < 2; ++mt) {
            #pragma unroll
            for (int i = 0; i < 4; ++i) {
                int m = mt * 16 + kq * 4 + i;
                if (m >= 20) continue;
                #pragma unroll
                for (int nt = 0; nt < 2; ++nt) {
                    int n = n0 + w * 32 + nt * 16 + l15;
                    Cb[(long long)m * 2048 + n] = acc[mt][nt][i];
                }
            }
        }
    } else {
        auto Xs = (float (*)[32])SMEM;              // [156][32]
        int* p  = (int*)(SMEM + 19968);             // [156]

        const int r0 = bx * 32;
        for (int i = tid; i < 156; i += 256) p[i] = perm[i];

        const int row = tid & 31;
        const int cq  = tid >> 5;
        #pragma unroll
        for (int it = 0; it < 20; ++it) {
            int c = it * 8 + cq;
            if (c < 156) {
                long long base = (long long)c * 16384 + r0 + row;
                float s = bf2f(Zp[base]) + bf2f(Zp[base + 2555904]);
                Xs[c][row] = s;
            }
        }
        __syncthreads();

        if (tid < 32) {
            float y = 0.f;
            for (int c = 0; c < 156; ++c) {
                y = ALPHA * y + Xs[p[c]][tid];
                L1T[(long long)c * 16384 + r0 + tid] = (y >= THETA) ? BF1 : 0;
            }
        }
    }
}

// ---------------------------------------------------------------------------
// MEGA3: blocks [0,32)   = branch-2 GEMM2 + fused out-scan — FIRST (LPT)
//        blocks [32,672) = branch-1 final T-scan (shuffle scan)  (r11)
// ---------------------------------------------------------------------------
__global__ __launch_bounds__(256) void mega_stage3(
    const float* __restrict__ C2p, float* __restrict__ out,
    const unsigned short* __restrict__ Wl2p,
    const unsigned short* __restrict__ L1T)
{
    __shared__ alignas(16) unsigned char SMEM[36864];
    const int bx  = blockIdx.x;
    const int tid = threadIdx.x;

    if (bx >= 32) {
        const int row = bx - 32;
        const float* x = C2p + (long long)row * 2048 + tid * 8;

        float v[8];
        *(f32x4v*)&v[0] = *(const f32x4v*)x;
        *(f32x4v*)&v[4] = *(const f32x4v*)(x + 4);

        float y = 0.f;
        #pragma unroll
        for (int k = 0; k < 8; ++k) { y = ALPHA * y + v[k]; v[k] = y; }

        const int lane = tid & 63, wid = tid >> 6;
        float val = y, mm = ALPHA8;
        #pragma unroll
        for (int d = 1; d < 64; d <<= 1) {
            float p = __shfl_up(val, d);
            if (lane >= d) val += mm * p;
            mm *= mm;
        }
        float* wsum = (float*)SMEM;
        if (lane == 63) wsum[wid] = val;
        __syncthreads();
        float pw = 0.f;
        #pragma unroll
        for (int w2 = 0; w2 < 3; ++w2)
            if (w2 < wid) pw = pw * A64C + wsum[w2];
        float prev = __shfl_up(val, 1);
        float a8l  = __expf(-0.8f * (float)lane);
        float carry = (lane == 0) ? pw : (prev + a8l * pw);

        float* o = out + (long long)row * 2204 + tid * 8;
        float ak = ALPHA;
        #pragma unroll
        for (int k = 0; k < 8; ++k) {
            float yk = v[k] + ak * carry;
            ak *= ALPHA;
            o[k] = (yk >= THETA) ? 1.0f : 0.0f;
        }
    } else {
        auto As = (unsigned short (*)[32][72])SMEM;         // [2][32][72] : 9216 B
        auto Bs = (unsigned short (*)[72])(SMEM + 9216);    // [192][72]  : 27648 B

        const int b  = bx;
        const int lane = tid & 63, w = tid >> 6;
        const int l15 = lane & 15, kq = lane >> 4;

        f32x4 acc[2][3] = {};

        for (int k0 = 0; k0 < 512; k0 += 64) {
            #pragma unroll
            for (int s = 0; s < 2; ++s) {
                int id = tid + s * 256;
                int pl = id >> 8, rem = id & 255;
                int m = rem >> 3, k8 = (rem & 7) * 8;
                ushort8v v = *(const ushort8v*)(Wl2p + (long long)pl * 16384 +
                                                (long long)m * 512 + k0 + k8);
                *(ushort8v*)&As[pl][m][k8] = v;
            }
            #pragma unroll
            for (int s = 0; s < 6; ++s) {
                int id = tid + s * 256;
                int n = id >> 3, k8 = (id & 7) * 8;
                ushort8v v = {0,0,0,0,0,0,0,0};
                if (n < 156)
                    v = *(const ushort8v*)(L1T + (long long)n * 16384 +
                                           b * 512 + k0 + k8);
                *(ushort8v*)&Bs[n][k8] = v;
            }
            __syncthreads();

            #pragma unroll
            for (int ks = 0; ks < 2; ++ks) {
                bf16x8 bfr[3];
                #pragma unroll
                for (int nt = 0; nt < 3; ++nt)
                    bfr[nt] = *(const bf16x8*)&Bs[w * 48 + nt * 16 + l15][ks * 32 + kq * 8];
                #pragma unroll
                for (int s = 0; s < 2; ++s) {
                    #pragma unroll
                    for (int mt = 0; mt < 2; ++mt) {
                        bf16x8 afr = *(const bf16x8*)&As[s][mt * 16 + l15][ks * 32 + kq * 8];
                        #pragma unroll
                        for (int nt = 0; nt < 3; ++nt)
                            acc[mt][nt] = __builtin_amdgcn_mfma_f32_16x16x32_bf16(
                                afr, bfr[nt], acc[mt][nt], 0, 0, 0);
                    }
                }
            }
            __syncthreads();
        }

        float* Cs = (float*)SMEM;                   // [32][193] = 24704 B
        #pragma unroll
        for (int mt = 0; mt < 2; ++mt) {
            #pragma unroll
            for (int i = 0; i < 4; ++i) {
                int m = mt * 16 + kq * 4 + i;
                #pragma unroll
                for (int nt = 0; nt < 3; ++nt) {
                    int n = w * 48 + nt * 16 + l15;
                    Cs[m * 193 + n] = acc[mt][nt][i];
                }
            }
        }
        __syncthreads();

        if (tid < 20) {
            const float* cr = Cs + tid * 193;
            float* o = out + (long long)(b * 20 + tid) * 2204 + 2048;
            float y = 0.f;
            for (int c = 0; c < 156; ++c) {
                y = ALPHA * y + cr[c];
                o[c] = (y >= THETA) ? 1.0f : 0.0f;
            }
        }
    }
}

// ---------------------------------------------------------------------------
// B=32, C_IN=156, T=2048, HID=512, OUT=20. Output [32,20,2204].
// ---------------------------------------------------------------------------
extern "C" void kernel_launch(void* const* d_in, const int* in_sizes, int n_in,
                              void* d_out, int out_size, void* d_ws, size_t ws_size,
                              hipStream_t stream)
{
    const float* In  = (const float*)d_in[0];  // [32][156][2048]
    const float* W1  = (const float*)d_in[1];  // [512][156]
    const float* W2  = (const float*)d_in[2];  // [20][512]
    const float* Wl1 = (const float*)d_in[3];  // [512][2048]
    const float* Wl2 = (const float*)d_in[4];  // [20][512]
    const int*  perm = (const int*)d_in[5];    // [156]
    float* out = (float*)d_out;                // [32][20][2204]

    float* ws = (float*)d_ws;
    // Disjoint layout (float offsets; ws is 256 MiB):
    unsigned short* S1bits = (unsigned short*)ws;              // [32][128][512]
    float* C2p = ws + 1048576LL;                               // [32][20][2048] final
    unsigned char*  Infp8 = (unsigned char*)(ws + 3670016LL);  // [4992][2048] fp8
    unsigned short* Pbf  = (unsigned short*)(ws + 6225920LL);  // [32][160][2048] bf16
    unsigned short* W1p  = (unsigned short*)(ws + 16580608LL); // [2][512][160]
    unsigned char*  W2p8 = (unsigned char*)(ws + 16662528LL);  // [2][32][512] fp8
    unsigned char*  Wl1p8= (unsigned char*)(ws + 16670720LL);  // [2][512][2048] fp8
    unsigned short* Wl2p = (unsigned short*)(ws + 17195008LL); // [2][32][512]
    unsigned short* Zpbf = (unsigned short*)(ws + 17211392LL); // [2][156][16384] bf16
    unsigned short* L1T  = (unsigned short*)(ws + 22323200LL); // [156][16384]

    dim3 blk(256);

    // ---- Preprocess (fused scan + pack; Pbf padded to 160 c-rows) ----
    prep_scan_pack<<<dim3(6208), blk, 0, stream>>>(
        In, Infp8, Pbf, W1, W2, Wl1, Wl2, W1p, W2p8, Wl1p8, Wl2p);

    // ---- Stage 1: both branch GEMM1s (branch-2 K=1024 first, LPT) ----
    mega_gemm1<<<dim3(2368), blk, 0, stream>>>(W1p, Pbf, S1bits,
                                               Wl1p8, Infp8, Zpbf);
    // ---- Stage 2: branch-2 perm-scan first, then branch-1 GEMM2 (full-K) ----
    mega_stage2<<<dim3(1024), blk, 0, stream>>>(W2p8, S1bits, C2p,
                                                Zpbf, perm, L1T);
    // ---- Stage 3: branch-2 GEMM2 (+fused out scan) first, then T-scans ----
    mega_stage3<<<dim3(672), blk, 0, stream>>>(C2p, out, Wl2p, L1T);

    (void)in_sizes; (void)n_in; (void)out_size; (void)ws_size;
}

// Round 13
// 170.051 us; speedup vs baseline: 1.0378x; 1.0155x over previous
//
#include <hip/hip_runtime.h>

// SLAYER constants
#define ALPHA  0.90483741803595952f   /* exp(-1/10) */
#define ALPHA8 0.44932896411722156f   /* exp(-0.8)  */
#define A64C   5.82e-23f              /* ALPHA8^64 = exp(-51.2), negligible tail */
#define THETA  10.0f
#define BF1    ((unsigned short)0x3F80) /* 1.0f as bf16 */
#define ISCALE 0.015625f               /* 1/64, exact */

typedef short   bf16x8 __attribute__((ext_vector_type(8)));
typedef float   f32x4  __attribute__((ext_vector_type(4)));
typedef float   f32x4v __attribute__((ext_vector_type(4)));
typedef unsigned short ushort4v __attribute__((ext_vector_type(4)));
typedef unsigned short ushort8v __attribute__((ext_vector_type(8)));
typedef unsigned char  uchar4v  __attribute__((ext_vector_type(4)));
typedef unsigned char  uchar8v  __attribute__((ext_vector_type(8)));
typedef long long i64;

// async global->LDS DMA, 16 B per lane. LDS dest = wave-uniform base + lane*16
#define DMA16(gsrc, ldst)                                                     \
    __builtin_amdgcn_global_load_lds(                                         \
        (const __attribute__((address_space(1))) unsigned int*)(gsrc),        \
        (__attribute__((address_space(3))) unsigned int*)(ldst), 16, 0, 0)

// HW transpose-read: 4x16 bf16 subtile, lane l elem j <- lds[(l&15)*2 + j*32
// + (l>>4)*128 + vaddr].  AS3 pointer (32-bit) as vaddr.
__device__ __forceinline__ i64 tr16(const unsigned char* p) {
    i64 r;
    asm volatile("ds_read_b64_tr_b16 %0, %1"
                 : "=v"(r)
                 : "v"((const __attribute__((address_space(3))) unsigned char*)p));
    return r;
}

// RNE float -> bf16 bits
__device__ __forceinline__ unsigned short f2bf(float f) {
    unsigned int x = __float_as_uint(f);
    unsigned int r = (x + 0x7FFFu + ((x >> 16) & 1u)) >> 16;
    return (unsigned short)r;
}
__device__ __forceinline__ float bf2f(unsigned short h) {
    return __uint_as_float(((unsigned int)h) << 16);
}
// 2-way bf16 split: w ~= h0+h1 (residual ~2^-17 rel)
__device__ __forceinline__ void split2(float w, unsigned short& h0,
                                       unsigned short& h1) {
    h0 = f2bf(w);          float r0 = w - bf2f(h0);
    h1 = f2bf(r0);
}
// HW fp8 converts
__device__ __forceinline__ unsigned char f2fp8(float f) {
    int pk = __builtin_amdgcn_cvt_pk_fp8_f32(f, 0.f, 0, false);
    return (unsigned char)(pk & 0xFF);
}
__device__ __forceinline__ float fp82f(unsigned char b) {
    return __builtin_amdgcn_cvt_f32_fp8((int)b, 0);
}

// ---------------------------------------------------------------------------
// prep_scan_pack: fused input prep + weight packing.  (r12, unchanged)
// Pbf is [32][160][2048] (c padded to 160 with ZERO rows).
// ---------------------------------------------------------------------------
__global__ __launch_bounds__(256) void prep_scan_pack(
    const float* __restrict__ In, unsigned char* __restrict__ Infp8,
    unsigned short* __restrict__ Pbf,
    const float* __restrict__ W1,  const float* __restrict__ W2,
    const float* __restrict__ Wl1, const float* __restrict__ Wl2,
    unsigned short* __restrict__ W1p,  unsigned char* __restrict__ W2p8,
    unsigned char* __restrict__ Wl1p8, unsigned short* __restrict__ Wl2p)
{
    const int blk = blockIdx.x;
    const int tid = threadIdx.x;
    if (blk >= 6080) {                          // Pbf zero-pad rows c=156..159
        int idx = blk - 6080;
        int b = idx >> 2, c = 156 + (idx & 3);
        ushort8v z = {0,0,0,0,0,0,0,0};
        *(ushort8v*)(Pbf + (long long)(b * 160 + c) * 2048 + tid * 8) = z;
        return;
    }
    if (blk < 1088) {
        if (blk < 512) {                            // Wl1 -> fp8 split-2, x64
            int m = blk;
            for (int k = tid; k < 2048; k += 256) {
                float w = Wl1[(long long)m * 2048 + k] * 64.0f;
                unsigned char h0 = f2fp8(w);
                unsigned char h1 = f2fp8(w - fp82f(h0));
                Wl1p8[(long long)m * 2048 + k] = h0;
                Wl1p8[1048576 + (long long)m * 2048 + k] = h1;
            }
        } else if (blk < 1024) {                    // W1 -> bf16 split-2
            int m = blk - 512;
            for (int k = tid; k < 160; k += 256) {
                float v = (k < 156) ? W1[(long long)m * 156 + k] : 0.f;
                unsigned short h0, h1;
                split2(v, h0, h1);
                W1p[(long long)m * 160 + k] = h0;
                W1p[81920 + (long long)m * 160 + k] = h1;
            }
        } else if (blk < 1056) {                    // W2 -> fp8 split-2
            int m = blk - 1024;
            for (int k = tid; k < 512; k += 256) {
                float w = (m < 20) ? W2[(long long)m * 512 + k] : 0.f;
                unsigned char h0 = f2fp8(w);
                unsigned char h1 = f2fp8(w - fp82f(h0));
                W2p8[(long long)m * 512 + k] = h0;
                W2p8[16384 + (long long)m * 512 + k] = h1;
            }
        } else {                                    // Wl2 -> bf16 split-2
            int m = blk - 1056;
            for (int k = tid; k < 512; k += 256) {
                float v = (m < 20) ? Wl2[(long long)m * 512 + k] : 0.f;
                unsigned short h0, h1;
                split2(v, h0, h1);
                Wl2p[(long long)m * 512 + k] = h0;
                Wl2p[16384 + (long long)m * 512 + k] = h1;
            }
        }
        return;
    }

    const int row = blk - 1088;
    const int bN  = row / 156;
    const int prow = bN * 160 + (row - bN * 156);
    const float* x = In + (long long)row * 2048 + tid * 8;
    const unsigned char ONE8 = f2fp8(1.0f);

    float v[8];
    *(f32x4v*)&v[0] = *(const f32x4v*)x;
    *(f32x4v*)&v[4] = *(const f32x4v*)(x + 4);

    uchar8v raw;
    #pragma unroll
    for (int k = 0; k < 8; ++k) raw[k] = (v[k] >= 0.5f) ? ONE8 : (unsigned char)0;
    *(uchar8v*)(Infp8 + (long long)row * 2048 + tid * 8) = raw;

    float y = 0.f;
    #pragma unroll
    for (int k = 0; k < 8; ++k) { y = ALPHA * y + v[k]; v[k] = y; }

    const int lane = tid & 63, wid = tid >> 6;
    float val = y, mm = ALPHA8;
    #pragma unroll
    for (int d = 1; d < 64; d <<= 1) {
        float p = __shfl_up(val, d);
        if (lane >= d) val += mm * p;
        mm *= mm;
    }
    __shared__ float wsum[4];
    if (lane == 63) wsum[wid] = val;
    __syncthreads();
    float pw = 0.f;
    #pragma unroll
    for (int w2 = 0; w2 < 3; ++w2)
        if (w2 < wid) pw = pw * A64C + wsum[w2];
    float prev = __shfl_up(val, 1);
    float a8l  = __expf(-0.8f * (float)lane);
    float carry = (lane == 0) ? pw : (prev + a8l * pw);

    ushort8v pv;
    float ak = ALPHA;
    #pragma unroll
    for (int k = 0; k < 8; ++k) {
        float yk = v[k] + ak * carry;
        ak *= ALPHA;
        pv[k] = f2bf(yk);
    }
    *(ushort8v*)(Pbf + (long long)prow * 2048 + tid * 8) = pv;
}

// ---------------------------------------------------------------------------
// MEGA1: blocks [0,160)   = branch-2 GEMM1 (fp8, 128x128 tile, FULL K=2048,
//                           32 K-steps) — first (LPT).  Zp is now ONE plane
//                           (-10 MB traffic vs r12), single f32 acc chain.
//        blocks [160,2208) = branch-1 GEMM1 (bf16, 128x128, tr16 B from Pbf)
// ---------------------------------------------------------------------------
__global__ __launch_bounds__(256) void mega_gemm1(
    const unsigned short* __restrict__ W1p,
    const unsigned short* __restrict__ Pbf,  // [32][160][2048] bf16
    unsigned short* __restrict__ S1bits,     // [32][128 nchunk][512 m]
    const unsigned char* __restrict__ Wl1p8, // [2][512][2048] fp8
    const unsigned char* __restrict__ Infp8, // [4992][2048] fp8
    unsigned short* __restrict__ Zp)         // [156][16384] c-major bf16
{
    __shared__ alignas(16) unsigned char SMEM[49152];
    const int bx  = blockIdx.x;
    const int tid = threadIdx.x;
    const int lane = tid & 63, w = tid >> 6;
    const int wy = w >> 1, wx = w & 1;
    const int l15 = lane & 15, kq = lane >> 4;
    const int key = (l15 >> 1) & 3;          // swizzle key (A-side)

    if (bx >= 160) {
        // ========== branch-1 GEMM1 (bf16, 128x128, DMA staging) ==========
        unsigned char* Ab = SMEM;                  // [2buf][2pl][128m][32k] 2x16384
        unsigned char* Bb = SMEM + 32768;          // [2buf] tr16-subtiled   2x8192

        const int id1 = bx - 160;
        const int z  = id1 >> 6;
        const int m0 = ((id1 >> 4) & 3) * 128;
        const int n0 = (id1 & 15) * 128;

        const unsigned short* gA[4]; int ldsA[4];
        #pragma unroll
        for (int s = 0; s < 4; ++s) {
            int id = tid + s * 256;
            int pl = id >> 9, m = (id >> 2) & 127, g = id & 3;
            int gs = g ^ ((m >> 1) & 3);
            gA[s] = W1p + (long long)pl * 81920 + (long long)(m0 + m) * 160 + gs * 8;
            ldsA[s] = id * 16;
        }
        // B source: lane id -> (c, t8) of the subtiled layout (dest = id*16)
        const unsigned short* gB[2];
        #pragma unroll
        for (int s = 0; s < 2; ++s) {
            int id = tid + s * 256;
            int c  = ((id >> 6) << 2) | ((id >> 1) & 3);
            int t8 = ((((id >> 3) & 7) << 1) | (id & 1)) << 3;
            gB[s] = Pbf + (long long)(z * 160 + c) * 2048 + n0 + t8;
        }

        auto dmaA = [&](int buf) {
            unsigned char* dst = Ab + buf * 16384;
            #pragma unroll
            for (int s = 0; s < 4; ++s) { DMA16(gA[s], dst + ldsA[s]); gA[s] += 32; }
        };
        auto dmaB = [&](int buf) {
            unsigned char* dst = Bb + buf * 8192;
            #pragma unroll
            for (int s = 0; s < 2; ++s) {
                DMA16(gB[s], dst + (tid + s * 256) * 16);
                gB[s] += 65536;                  // +32 c rows
            }
        };

        int aOff[2][4];
        #pragma unroll
        for (int pl = 0; pl < 2; ++pl)
            #pragma unroll
            for (int mt = 0; mt < 4; ++mt)
                aOff[pl][mt] = pl * 8192 + (wy * 64 + mt * 16 + l15) * 64 +
                               ((kq ^ key) * 16);
        // tr16 base: quarter skew kq*1920 (+ HW kq*128 = subtile stride 2048)
        const int bTr = wx * 512 + kq * 1920;

        f32x4 acc[4][4] = {};

        dmaA(0); dmaB(0);
        __syncthreads();

        #pragma unroll
        for (int it = 0; it < 5; ++it) {
            const int cur = it & 1;
            if (it < 4) { dmaA(cur ^ 1); dmaB(cur ^ 1); }

            const unsigned char* Ac = Ab + cur * 16384;
            const unsigned char* vB = Bb + cur * 8192 + bTr;
            bf16x8 bfr[4];
            #pragma unroll
            for (int nt = 0; nt < 4; ++nt) {
                union { i64 q[2]; bf16x8 v; } u;
                u.q[0] = tr16(vB + nt * 128);            // c = kq*8+0..3
                u.q[1] = tr16(vB + 1024 + nt * 128);     // c = kq*8+4..7
                bfr[nt] = u.v;
            }
            asm volatile("s_waitcnt lgkmcnt(0)" ::: "memory");
            __builtin_amdgcn_sched_barrier(0);

            #pragma unroll
            for (int pl = 0; pl < 2; ++pl) {
                #pragma unroll
                for (int mt = 0; mt < 4; ++mt) {
                    bf16x8 afr = *(const bf16x8*)(Ac + aOff[pl][mt]);
                    #pragma unroll
                    for (int nt = 0; nt < 4; ++nt)
                        acc[mt][nt] = __builtin_amdgcn_mfma_f32_16x16x32_bf16(
                            afr, bfr[nt], acc[mt][nt], 0, 0, 0);
                }
            }
            __syncthreads();
        }

        unsigned short* Db = S1bits + (long long)z * 512 * 128;
        #pragma unroll
        for (int mt = 0; mt < 4; ++mt) {
            #pragma unroll
            for (int i = 0; i < 4; ++i) {
                int m = m0 + wy * 64 + mt * 16 + kq * 4 + i;
                #pragma unroll
                for (int nt = 0; nt < 4; ++nt) {
                    unsigned long long mask = __ballot(acc[mt][nt][i] >= THETA);
                    if (l15 == 0) {
                        int nchunk = (n0 + wx * 64 + nt * 16) >> 4;
                        Db[(long long)nchunk * 512 + m] =
                            (unsigned short)((mask >> (kq * 16)) & 0xFFFFu);
                    }
                }
            }
        }
    } else {
        // ========== branch-2 GEMM1 (fp8, 128x128, K=2048, DMA staging) =====
        unsigned char* Ab = SMEM;                  // [2buf][2pl][128m][64k] 2x16384
        unsigned char* Bb = SMEM + 32768;          // [2buf][128n][64k]      2x8192

        const int id0 = bx;
        const int nIdx = id0 % 40;
        if (nIdx >= 39) return;
        const int rest = id0 / 40;                 // 0..3
        const int n0  = nIdx * 128;
        const int m0  = rest * 128;

        const unsigned char* gA8[4]; int ldsA8[4];
        #pragma unroll
        for (int s = 0; s < 4; ++s) {
            int id = tid + s * 256;
            int pl = id >> 9, m = (id >> 2) & 127, g = id & 3;
            int gs = g ^ ((m >> 1) & 3);
            gA8[s] = Wl1p8 + (long long)pl * 1048576 +
                     (long long)(m0 + m) * 2048 + gs * 16;
            ldsA8[s] = id * 16;
        }
        const unsigned char* gB8[2]; int ldsB8[2];
        #pragma unroll
        for (int s = 0; s < 2; ++s) {
            int id = tid + s * 256;
            int n = id >> 2, g = id & 3;
            int gs = g ^ ((n >> 1) & 3);
            gB8[s] = Infp8 + (long long)(n0 + n) * 2048 + gs * 16;
            ldsB8[s] = id * 16;
        }

        auto dmaA8 = [&](int buf) {
            unsigned char* dst = Ab + buf * 16384;
            #pragma unroll
            for (int s = 0; s < 4; ++s) { DMA16(gA8[s], dst + ldsA8[s]); gA8[s] += 64; }
        };
        auto dmaB8 = [&](int buf) {
            unsigned char* dst = Bb + buf * 8192;
            #pragma unroll
            for (int s = 0; s < 2; ++s) { DMA16(gB8[s], dst + ldsB8[s]); gB8[s] += 64; }
        };

        int aO8[2][4][2], bO8[4][2];
        #pragma unroll
        for (int ks = 0; ks < 2; ++ks) {
            const int gl = ks * 2 + (kq >> 1);
            const int sub = ((gl ^ key) * 16) + (kq & 1) * 8;
            #pragma unroll
            for (int pl = 0; pl < 2; ++pl)
                #pragma unroll
                for (int mt = 0; mt < 4; ++mt)
                    aO8[pl][mt][ks] = pl * 8192 +
                        (wy * 64 + mt * 16 + l15) * 64 + sub;
            #pragma unroll
            for (int nt = 0; nt < 4; ++nt)
                bO8[nt][ks] = (wx * 64 + nt * 16 + l15) * 64 + sub;
        }

        f32x4 acc[4][4] = {};

        dmaA8(0); dmaB8(0);
        __syncthreads();

        for (int it = 0; it < 32; ++it) {
            const int cur = it & 1;
            if (it < 31) { dmaA8(cur ^ 1); dmaB8(cur ^ 1); }

            const unsigned char* Ac = Ab + cur * 16384;
            const unsigned char* Bc = Bb + cur * 8192;
            #pragma unroll
            for (int ks = 0; ks < 2; ++ks) {
                i64 bfr[4];
                #pragma unroll
                for (int nt = 0; nt < 4; ++nt)
                    bfr[nt] = *(const i64*)(Bc + bO8[nt][ks]);
                #pragma unroll
                for (int pl = 0; pl < 2; ++pl) {
                    #pragma unroll
                    for (int mt = 0; mt < 4; ++mt) {
                        i64 afr = *(const i64*)(Ac + aO8[pl][mt][ks]);
                        #pragma unroll
                        for (int nt = 0; nt < 4; ++nt)
                            acc[mt][nt] = __builtin_amdgcn_mfma_f32_16x16x32_fp8_fp8(
                                afr, bfr[nt], acc[mt][nt], 0, 0, 0);
                    }
                }
            }
            __syncthreads();
        }

        unsigned short* Tu = (unsigned short*)SMEM;   // [128][130] overlay
        #pragma unroll
        for (int mt = 0; mt < 4; ++mt) {
            #pragma unroll
            for (int i = 0; i < 4; ++i) {
                int mL = wy * 64 + mt * 16 + kq * 4 + i;
                #pragma unroll
                for (int nt = 0; nt < 4; ++nt) {
                    int nL = wx * 64 + nt * 16 + l15;
                    Tu[mL * 130 + nL] = f2bf(acc[mt][nt][i] * ISCALE);
                }
            }
        }
        __syncthreads();

        #pragma unroll
        for (int s2 = 0; s2 < 64; ++s2) {
            int id = tid + s2 * 256;
            int cL = id >> 7;
            int mL = id & 127;
            int n = n0 + cL;
            int bb = n / 156, cc = n - bb * 156;
            Zp[(long long)cc * 16384 + bb * 512 + m0 + mL] = Tu[mL * 130 + cL];
        }
    }
}

// ---------------------------------------------------------------------------
// MEGA2: blocks [0,512)    = branch-2 scan_perm (single-plane Zp) — first
//        blocks [512,1024) = branch-1 GEMM2 (fp8 MFMA, full K=512)  (r12)
// ---------------------------------------------------------------------------
__global__ __launch_bounds__(256) void mega_stage2(
    const unsigned char* __restrict__ W2p8,
    const unsigned short* __restrict__ S1bits,   // [32][128 nchunk][512 m]
    float* __restrict__ C2p,                     // [32][20][2048] final
    const unsigned short* __restrict__ Zp,       // [156][16384] bf16
    const int* __restrict__ perm,
    unsigned short* __restrict__ L1T)
{
    __shared__ alignas(16) unsigned char SMEM[27648];
    const int bx  = blockIdx.x;
    const int tid = threadIdx.x;

    if (bx >= 512) {
        auto As = (unsigned char (*)[2][32][72])SMEM;         // [buf][pl][32][72] : 2x4608
        auto Bs = (unsigned char (*)[128][72])(SMEM + 9216);  // [buf][128][72]    : 2x9216

        const int bxg = bx - 512;
        const int lane = tid & 63, w = tid >> 6;
        const int l15 = lane & 15, kq = lane >> 4;
        const int n0  = (bxg & 15) * 128;
        const int b   = bxg >> 4;

        const unsigned short* Bb = S1bits + (long long)b * 512 * 128;
        const unsigned char ONE8 = f2fp8(1.0f);

        int aPl[2], aM[2], aK8[2];
        #pragma unroll
        for (int s = 0; s < 2; ++s) {
            int id = tid + s * 256;
            aPl[s] = id >> 8; int rem = id & 255;
            aM[s] = rem >> 3; aK8[s] = (rem & 7) * 8;
        }
        const int kb = (tid >> 4) * 4;
        const int nb = (tid & 15) * 8;
        const int nchunk = (n0 + nb) >> 4;
        const int nshift = nb & 15;

        f32x4 acc[2][2] = {};
        uchar8v aReg[2];
        unsigned short bBits[4];

        auto loadA = [&](int k0) {
            #pragma unroll
            for (int s = 0; s < 2; ++s)
                aReg[s] = *(const uchar8v*)(W2p8 + (long long)aPl[s] * 16384 +
                                            (long long)aM[s] * 512 + k0 + aK8[s]);
        };
        auto loadB = [&](int k0) {
            unsigned long long u = *(const unsigned long long*)
                (Bb + (long long)nchunk * 512 + k0 + kb);
            bBits[0] = (unsigned short)u;
            bBits[1] = (unsigned short)(u >> 16);
            bBits[2] = (unsigned short)(u >> 32);
            bBits[3] = (unsigned short)(u >> 48);
        };
        auto stage = [&](int buf) {
            #pragma unroll
            for (int s = 0; s < 2; ++s) *(uchar8v*)&As[buf][aPl[s]][aM[s]][aK8[s]] = aReg[s];
            unsigned char bv[4][8];
            #pragma unroll
            for (int kk2 = 0; kk2 < 4; ++kk2) {
                unsigned int bits = ((unsigned int)bBits[kk2] >> nshift) & 0xFFu;
                #pragma unroll
                for (int j = 0; j < 8; ++j)
                    bv[kk2][j] = ((bits >> j) & 1u) ? ONE8 : (unsigned char)0;
            }
            #pragma unroll
            for (int j = 0; j < 8; ++j) {
                uchar4v v4 = { bv[0][j], bv[1][j], bv[2][j], bv[3][j] };
                *(uchar4v*)&Bs[buf][nb + j][kb] = v4;
            }
        };

        loadA(0); loadB(0);
        stage(0);
        __syncthreads();

        #pragma unroll
        for (int it = 0; it < 8; ++it) {
            const int cur = it & 1;
            const int kn = (it + 1) * 64;
            if (it < 7) { loadA(kn); loadB(kn); }

            #pragma unroll
            for (int ks = 0; ks < 2; ++ks) {
                i64 bfr[2];
                #pragma unroll
                for (int nt = 0; nt < 2; ++nt)
                    bfr[nt] = *(const i64*)&Bs[cur][w * 32 + nt * 16 + l15][ks * 32 + kq * 8];
                #pragma unroll
                for (int pl = 0; pl < 2; ++pl) {
                    #pragma unroll
                    for (int mt = 0; mt < 2; ++mt) {
                        i64 afr = *(const i64*)&As[cur][pl][mt * 16 + l15][ks * 32 + kq * 8];
                        #pragma unroll
                        for (int nt = 0; nt < 2; ++nt)
                            acc[mt][nt] = __builtin_amdgcn_mfma_f32_16x16x32_fp8_fp8(
                                afr, bfr[nt], acc[mt][nt], 0, 0, 0);
                    }
                }
            }

            if (it < 7) stage(cur ^ 1);
            __syncthreads();
        }

        float* Cb = C2p + (long long)b * 20 * 2048;
        #pragma unroll
        for (int mt = 0; mt < 2; ++mt) {
            #pragma unroll
            for (int i = 0; i < 4; ++i) {
                int m = mt * 16 + kq * 4 + i;
                if (m >= 20) continue;
                #pragma unroll
                for (int nt = 0; nt < 2; ++nt) {
                    int n = n0 + w * 32 + nt * 16 + l15;
                    Cb[(long long)m * 2048 + n] = acc[mt][nt][i];
                }
            }
        }
    } else {
        auto Xs = (float (*)[32])SMEM;              // [156][32]
        int* p  = (int*)(SMEM + 19968);             // [156]

        const int r0 = bx * 32;
        for (int i = tid; i < 156; i += 256) p[i] = perm[i];

        const int row = tid & 31;
        const int cq  = tid >> 5;
        #pragma unroll
        for (int it = 0; it < 20; ++it) {
            int c = it * 8 + cq;
            if (c < 156) {
                Xs[c][row] = bf2f(Zp[(long long)c * 16384 + r0 + row]);
            }
        }
        __syncthreads();

        if (tid < 32) {
            float y = 0.f;
            for (int c = 0; c < 156; ++c) {
                y = ALPHA * y + Xs[p[c]][tid];
                L1T[(long long)c * 16384 + r0 + tid] = (y >= THETA) ? BF1 : 0;
            }
        }
    }
}

// ---------------------------------------------------------------------------
// MEGA3: blocks [0,32)   = branch-2 GEMM2 + fused out-scan — FIRST (LPT)
//        blocks [32,672) = branch-1 final T-scan (shuffle scan)  (r12)
// ---------------------------------------------------------------------------
__global__ __launch_bounds__(256) void mega_stage3(
    const float* __restrict__ C2p, float* __restrict__ out,
    const unsigned short* __restrict__ Wl2p,
    const unsigned short* __restrict__ L1T)
{
    __shared__ alignas(16) unsigned char SMEM[36864];
    const int bx  = blockIdx.x;
    const int tid = threadIdx.x;

    if (bx >= 32) {
        const int row = bx - 32;
        const float* x = C2p + (long long)row * 2048 + tid * 8;

        float v[8];
        *(f32x4v*)&v[0] = *(const f32x4v*)x;
        *(f32x4v*)&v[4] = *(const f32x4v*)(x + 4);

        float y = 0.f;
        #pragma unroll
        for (int k = 0; k < 8; ++k) { y = ALPHA * y + v[k]; v[k] = y; }

        const int lane = tid & 63, wid = tid >> 6;
        float val = y, mm = ALPHA8;
        #pragma unroll
        for (int d = 1; d < 64; d <<= 1) {
            float p = __shfl_up(val, d);
            if (lane >= d) val += mm * p;
            mm *= mm;
        }
        float* wsum = (float*)SMEM;
        if (lane == 63) wsum[wid] = val;
        __syncthreads();
        float pw = 0.f;
        #pragma unroll
        for (int w2 = 0; w2 < 3; ++w2)
            if (w2 < wid) pw = pw * A64C + wsum[w2];
        float prev = __shfl_up(val, 1);
        float a8l  = __expf(-0.8f * (float)lane);
        float carry = (lane == 0) ? pw : (prev + a8l * pw);

        float* o = out + (long long)row * 2204 + tid * 8;
        float ak = ALPHA;
        #pragma unroll
        for (int k = 0; k < 8; ++k) {
            float yk = v[k] + ak * carry;
            ak *= ALPHA;
            o[k] = (yk >= THETA) ? 1.0f : 0.0f;
        }
    } else {
        auto As = (unsigned short (*)[32][72])SMEM;         // [2][32][72] : 9216 B
        auto Bs = (unsigned short (*)[72])(SMEM + 9216);    // [192][72]  : 27648 B

        const int b  = bx;
        const int lane = tid & 63, w = tid >> 6;
        const int l15 = lane & 15, kq = lane >> 4;

        f32x4 acc[2][3] = {};

        for (int k0 = 0; k0 < 512; k0 += 64) {
            #pragma unroll
            for (int s = 0; s < 2; ++s) {
                int id = tid + s * 256;
                int pl = id >> 8, rem = id & 255;
                int m = rem >> 3, k8 = (rem & 7) * 8;
                ushort8v v = *(const ushort8v*)(Wl2p + (long long)pl * 16384 +
                                                (long long)m * 512 + k0 + k8);
                *(ushort8v*)&As[pl][m][k8] = v;
            }
            #pragma unroll
            for (int s = 0; s < 6; ++s) {
                int id = tid + s * 256;
                int n = id >> 3, k8 = (id & 7) * 8;
                ushort8v v = {0,0,0,0,0,0,0,0};
                if (n < 156)
                    v = *(const ushort8v*)(L1T + (long long)n * 16384 +
                                           b * 512 + k0 + k8);
                *(ushort8v*)&Bs[n][k8] = v;
            }
            __syncthreads();

            #pragma unroll
            for (int ks = 0; ks < 2; ++ks) {
                bf16x8 bfr[3];
                #pragma unroll
                for (int nt = 0; nt < 3; ++nt)
                    bfr[nt] = *(const bf16x8*)&Bs[w * 48 + nt * 16 + l15][ks * 32 + kq * 8];
                #pragma unroll
                for (int s = 0; s < 2; ++s) {
                    #pragma unroll
                    for (int mt = 0; mt < 2; ++mt) {
                        bf16x8 afr = *(const bf16x8*)&As[s][mt * 16 + l15][ks * 32 + kq * 8];
                        #pragma unroll
                        for (int nt = 0; nt < 3; ++nt)
                            acc[mt][nt] = __builtin_amdgcn_mfma_f32_16x16x32_bf16(
                                afr, bfr[nt], acc[mt][nt], 0, 0, 0);
                    }
                }
            }
            __syncthreads();
        }

        float* Cs = (float*)SMEM;                   // [32][193] = 24704 B
        #pragma unroll
        for (int mt = 0; mt < 2; ++mt) {
            #pragma unroll
            for (int i = 0; i < 4; ++i) {
                int m = mt * 16 + kq * 4 + i;
                #pragma unroll
                for (int nt = 0; nt < 3; ++nt) {
                    int n = w * 48 + nt * 16 + l15;
                    Cs[m * 193 + n] = acc[mt][nt][i];
                }
            }
        }
        __syncthreads();

        if (tid < 20) {
            const float* cr = Cs + tid * 193;
            float* o = out + (long long)(b * 20 + tid) * 2204 + 2048;
            float y = 0.f;
            for (int c = 0; c < 156; ++c) {
                y = ALPHA * y + cr[c];
                o[c] = (y >= THETA) ? 1.0f : 0.0f;
            }
        }
    }
}

// ---------------------------------------------------------------------------
// B=32, C_IN=156, T=2048, HID=512, OUT=20. Output [32,20,2204].
// ---------------------------------------------------------------------------
extern "C" void kernel_launch(void* const* d_in, const int* in_sizes, int n_in,
                              void* d_out, int out_size, void* d_ws, size_t ws_size,
                              hipStream_t stream)
{
    const float* In  = (const float*)d_in[0];  // [32][156][2048]
    const float* W1  = (const float*)d_in[1];  // [512][156]
    const float* W2  = (const float*)d_in[2];  // [20][512]
    const float* Wl1 = (const float*)d_in[3];  // [512][2048]
    const float* Wl2 = (const float*)d_in[4];  // [20][512]
    const int*  perm = (const int*)d_in[5];    // [156]
    float* out = (float*)d_out;                // [32][20][2204]

    float* ws = (float*)d_ws;
    // Disjoint layout (float offsets; ws is 256 MiB):
    unsigned short* S1bits = (unsigned short*)ws;              // [32][128][512]
    float* C2p = ws + 1048576LL;                               // [32][20][2048] final
    unsigned char*  Infp8 = (unsigned char*)(ws + 3670016LL);  // [4992][2048] fp8
    unsigned short* Pbf  = (unsigned short*)(ws + 6225920LL);  // [32][160][2048] bf16
    unsigned short* W1p  = (unsigned short*)(ws + 16580608LL); // [2][512][160]
    unsigned char*  W2p8 = (unsigned char*)(ws + 16662528LL);  // [2][32][512] fp8
    unsigned char*  Wl1p8= (unsigned char*)(ws + 16670720LL);  // [2][512][2048] fp8
    unsigned short* Wl2p = (unsigned short*)(ws + 17195008LL); // [2][32][512]
    unsigned short* Zpbf = (unsigned short*)(ws + 17211392LL); // [156][16384] bf16
    unsigned short* L1T  = (unsigned short*)(ws + 22323200LL); // [156][16384]

    dim3 blk(256);

    // ---- Preprocess (fused scan + pack; Pbf padded to 160 c-rows) ----
    prep_scan_pack<<<dim3(6208), blk, 0, stream>>>(
        In, Infp8, Pbf, W1, W2, Wl1, Wl2, W1p, W2p8, Wl1p8, Wl2p);

    // ---- Stage 1: both branch GEMM1s (branch-2 K=2048 first, LPT) ----
    mega_gemm1<<<dim3(2208), blk, 0, stream>>>(W1p, Pbf, S1bits,
                                               Wl1p8, Infp8, Zpbf);
    // ---- Stage 2: branch-2 perm-scan first, then branch-1 GEMM2 (full-K) ----
    mega_stage2<<<dim3(1024), blk, 0, stream>>>(W2p8, S1bits, C2p,
                                                Zpbf, perm, L1T);
    // ---- Stage 3: branch-2 GEMM2 (+fused out scan) first, then T-scans ----
    mega_stage3<<<dim3(672), blk, 0, stream>>>(C2p, out, Wl2p, L1T);

    (void)in_sizes; (void)n_in; (void)out_size; (void)ws_size;
}